// Round 1
// baseline (1342.284 us; speedup 1.0000x reference)
//
#include <hip/hip_runtime.h>

#define MM 64
#define NN 16
#define DDIM 300
#define FNUM 768
#define SURF_LL 4
#define CTX_LL 50
#define DOC_LL 100
#define BODY_LL 200
#define NHEADS 5
#define HDIM 60

// ---- workspace layout (float offsets) ----
#define OFF_MSG    0
#define OFF_CTXG   (OFF_MSG + MM*SURF_LL*DDIM)     // mention emb   [64][4][300]
#define OFF_CTX2G  (OFF_CTXG + MM*CTX_LL*DDIM)     // context_vec emb [64][50][300]
#define OFF_CANDG  (OFF_CTX2G + MM*CTX_LL*DDIM)    // contexts_ids emb [64][50][300]
#define OFF_MS     (OFF_CANDG + MM*NN*DDIM)        // cand emb [64][16][300]
#define OFF_MC     (OFF_MS + MM*FNUM)              // ms [64][768]
#define OFF_S      (OFF_MC + 2*MM*FNUM)            // mc partials [2][64][768]
#define OFF_ADB    (OFF_S + 160*20000)             // attention S/P buffers
#define OFF_ABD    (OFF_ADB + NN*DDIM)
#define OFF_ASC    (OFF_ABD + NN*DDIM)
#define OFF_TOKMAX (OFF_ASC + 16)
#define OFF_LATT   (OFF_TOKMAX + MM*CTX_LL)
#define WS_FLOATS  (OFF_LATT + MM*NN)

// ---------------------------------------------------------------------------
// Gather all needed embedding rows contiguously into ws.
// rows: [0,256) mention_vec -> msg ; [256,3456) context_vec -> ctxg ;
//       [3456,6656) contexts_ids -> ctx2g ; [6656,7680) men2cands -> candg
// total elems = 7680*300 = 2,304,000 = 9000 blocks * 256
__global__ __launch_bounds__(256) void gather_kernel(
    const float* __restrict__ embed,
    const int* __restrict__ mention_vec,
    const int* __restrict__ context_vec,
    const int* __restrict__ contexts_ids,
    const int* __restrict__ men2cands,
    float* __restrict__ dst) {
  int e = blockIdx.x * 256 + threadIdx.x;
  int row = e / DDIM;
  int col = e - row * DDIM;
  int tok;
  if (row < 256)       tok = mention_vec[row];
  else if (row < 3456) tok = context_vec[row - 256];
  else if (row < 6656) tok = contexts_ids[row - 3456];
  else                 tok = men2cands[row - 6656];
  dst[e] = embed[(size_t)tok * DDIM + col];
}

// ---------------------------------------------------------------------------
// conv_ms: kernel width 2 over L=4 -> 3 positions, relu, mean.  grid=64
__global__ __launch_bounds__(256) void conv_ms_kernel(
    const float* __restrict__ msg,   // [64][4][300]
    const float* __restrict__ W,     // [768][300][2]
    const float* __restrict__ B,
    float* __restrict__ ms) {        // [64][768]
  int m = blockIdx.x;
  const float* x0 = msg + (m * SURF_LL + 0) * DDIM;  // uniform addresses -> s_load
  const float* x1 = msg + (m * SURF_LL + 1) * DDIM;
  const float* x2 = msg + (m * SURF_LL + 2) * DDIM;
  const float* x3 = msg + (m * SURF_LL + 3) * DDIM;
  for (int f = threadIdx.x; f < FNUM; f += 256) {
    const float2* wf = (const float2*)(W + (size_t)f * 600);
    float a0 = 0.f, a1 = 0.f, a2 = 0.f;
    for (int d = 0; d < DDIM; d++) {
      float2 w = wf[d];
      float v0 = x0[d], v1 = x1[d], v2 = x2[d], v3 = x3[d];
      a0 += v0 * w.x + v1 * w.y;
      a1 += v1 * w.x + v2 * w.y;
      a2 += v2 * w.x + v3 * w.y;
    }
    float b = B[f];
    float r = fmaxf(a0 + b, 0.f) + fmaxf(a1 + b, 0.f) + fmaxf(a2 + b, 0.f);
    ms[m * FNUM + f] = r * (1.0f / 3.0f);
  }
}

// ---------------------------------------------------------------------------
// conv_mc: kernel width 5 over L=50 -> 46 positions, relu, mean over 46.
// grid = (m=64, th=2, ft=3); block=256, one filter/thread; each block covers
// t in [th*23, th*23+23).  Partial relu-sums -> mc2[th][m][f]; combined in
// final_kernel.  Activations read with block-uniform addresses (scalar pipe).
__global__ __launch_bounds__(256) void conv_mc_kernel(
    const float* __restrict__ ctxg,  // [64][50][300]
    const float* __restrict__ W,     // [768][300][5]
    const float* __restrict__ B,
    float* __restrict__ mc2) {       // [2][64][768]
  int m = blockIdx.x, th = blockIdx.y, ft = blockIdx.z;
  int f = ft * 256 + threadIdx.x;
  int t0 = th * 23;
  const float* x = ctxg + (size_t)(m * CTX_LL + t0) * DDIM;  // rows [0,27)
  const float* wf = W + (size_t)f * 1500;
  float acc[23];
#pragma unroll
  for (int i = 0; i < 23; i++) acc[i] = 0.f;
  for (int d = 0; d < DDIM; d++) {
    float w0 = wf[d * 5 + 0], w1 = wf[d * 5 + 1], w2 = wf[d * 5 + 2];
    float w3 = wf[d * 5 + 3], w4 = wf[d * 5 + 4];
    float xv[27];
#pragma unroll
    for (int j = 0; j < 27; j++) xv[j] = x[j * DDIM + d];  // uniform -> s_load
#pragma unroll
    for (int t = 0; t < 23; t++)
      acc[t] += xv[t] * w0 + xv[t + 1] * w1 + xv[t + 2] * w2 + xv[t + 3] * w3 +
                xv[t + 4] * w4;
  }
  float b = B[f];
  float s = 0.f;
#pragma unroll
  for (int t = 0; t < 23; t++) s += fmaxf(acc[t] + b, 0.f);
  mc2[(size_t)(th * MM + m) * FNUM + f] = s;
}

// ---------------------------------------------------------------------------
// Attention scores: S[n][dir][h][q][k] = (Q_h[q] . K_h[k]) / sqrt(60)
// DIR=0: q=doc(100), k=body[n](200).  DIR=1: q=body[n](200), k=doc(100).
// block=256 as 16x16 threads, 2x2 register tile -> 32x32 score tile.
template <int DIR>
__global__ __launch_bounds__(256) void scores_kernel(
    const float* __restrict__ embed,
    const int* __restrict__ doc_vec,
    const int* __restrict__ body_vec,
    float* __restrict__ S) {
  constexpr int Lq = DIR ? 200 : 100;
  constexpr int Lk = DIR ? 100 : 200;
  constexpr int KT = DIR ? 4 : 7;
  int n = blockIdx.y;
  int bx = blockIdx.x;
  int qt = bx / KT, kt = bx % KT;
  int tx = threadIdx.x & 15, ty = threadIdx.x >> 4;
  int q0 = qt * 32 + ty * 2, k0 = kt * 32 + tx * 2;
  const int* qids = DIR ? body_vec + n * BODY_LL : doc_vec;
  const int* kids = DIR ? doc_vec : body_vec + n * BODY_LL;
  int qa = min(q0, Lq - 1), qb = min(q0 + 1, Lq - 1);
  int ka = min(k0, Lk - 1), kb = min(k0 + 1, Lk - 1);
  const float4* Q0 = (const float4*)(embed + (size_t)qids[qa] * DDIM);
  const float4* Q1 = (const float4*)(embed + (size_t)qids[qb] * DDIM);
  const float4* K0 = (const float4*)(embed + (size_t)kids[ka] * DDIM);
  const float4* K1 = (const float4*)(embed + (size_t)kids[kb] * DDIM);
  float acc[NHEADS][4];
#pragma unroll
  for (int h = 0; h < NHEADS; h++)
#pragma unroll
    for (int i = 0; i < 4; i++) acc[h][i] = 0.f;
#pragma unroll
  for (int c = 0; c < 75; c++) {
    int h = c / 15;  // static after unroll
    float4 a0 = Q0[c], a1 = Q1[c], b0 = K0[c], b1 = K1[c];
    acc[h][0] += a0.x * b0.x + a0.y * b0.y + a0.z * b0.z + a0.w * b0.w;
    acc[h][1] += a0.x * b1.x + a0.y * b1.y + a0.z * b1.z + a0.w * b1.w;
    acc[h][2] += a1.x * b0.x + a1.y * b0.y + a1.z * b0.z + a1.w * b0.w;
    acc[h][3] += a1.x * b1.x + a1.y * b1.y + a1.z * b1.z + a1.w * b1.w;
  }
  const float scale = 0.12909944487358056f;  // 1/sqrt(60)
#pragma unroll
  for (int h = 0; h < NHEADS; h++) {
    float* Sh = S + (size_t)((n * 2 + DIR) * NHEADS + h) * 20000;
    if (q0 < Lq) {
      if (k0 < Lk) Sh[q0 * Lk + k0] = acc[h][0] * scale;
      if (k0 + 1 < Lk) Sh[q0 * Lk + k0 + 1] = acc[h][1] * scale;
    }
    if (q0 + 1 < Lq) {
      if (k0 < Lk) Sh[(q0 + 1) * Lk + k0] = acc[h][2] * scale;
      if (k0 + 1 < Lk) Sh[(q0 + 1) * Lk + k0 + 1] = acc[h][3] * scale;
    }
  }
}

// ---------------------------------------------------------------------------
// Row softmax over k, in place.  One wave per row; 24000 rows total.
__global__ __launch_bounds__(256) void softmax_kernel(float* __restrict__ S) {
  int wid = threadIdx.x >> 6, lane = threadIdx.x & 63;
  int r = blockIdx.x * 4 + wid;
  int n, dir, h, q, Lk;
  if (r < 8000) {
    dir = 0; n = r / 500; int rem = r - n * 500;
    h = rem / 100; q = rem - h * 100; Lk = 200;
  } else {
    int r2 = r - 8000;
    dir = 1; n = r2 / 1000; int rem = r2 - n * 1000;
    h = rem / 200; q = rem - h * 200; Lk = 100;
  }
  float* row = S + (size_t)((n * 2 + dir) * NHEADS + h) * 20000 + q * Lk;
  float v[4];
  float mx = -1e30f;
#pragma unroll
  for (int i = 0; i < 4; i++) {
    int e = lane + i * 64;
    v[i] = (e < Lk) ? row[e] : -1e30f;
    mx = fmaxf(mx, v[i]);
  }
#pragma unroll
  for (int o = 32; o >= 1; o >>= 1) mx = fmaxf(mx, __shfl_xor(mx, o));
  float s = 0.f;
#pragma unroll
  for (int i = 0; i < 4; i++) {
    int e = lane + i * 64;
    v[i] = (e < Lk) ? expf(v[i] - mx) : 0.f;
    s += v[i];
  }
#pragma unroll
  for (int o = 32; o >= 1; o >>= 1) s += __shfl_xor(s, o);
  float inv = 1.0f / s;
#pragma unroll
  for (int i = 0; i < 4; i++) {
    int e = lane + i * 64;
    if (e < Lk) row[e] = v[i] * inv;
  }
}

// ---------------------------------------------------------------------------
// PV + max-pool over q.  grid=(n=16, h=5).  lane d=tid&63 (<60 active),
// wave qg=tid>>6 owns q = qg+4i.  P rows are wave-uniform float4 loads.
template <int DIR>
__global__ __launch_bounds__(256) void pv_kernel(
    const float* __restrict__ embed,
    const int* __restrict__ doc_vec,
    const int* __restrict__ body_vec,
    const float* __restrict__ S,
    float* __restrict__ att_out) {  // [16][300]
  constexpr int Lq = DIR ? 200 : 100;
  constexpr int Lk = DIR ? 100 : 200;
  constexpr int NQ = Lq / 4;
  int n = blockIdx.x, h = blockIdx.y;
  const int* kids = DIR ? doc_vec : body_vec + n * BODY_LL;
  int d = threadIdx.x & 63;
  int qg = __builtin_amdgcn_readfirstlane(threadIdx.x >> 6);
  const float4* P4 = (const float4*)(S + (size_t)((n * 2 + DIR) * NHEADS + h) * 20000);
  float acc[NQ];
#pragma unroll
  for (int i = 0; i < NQ; i++) acc[i] = 0.f;
  for (int k = 0; k < Lk; k += 4) {
    int t0 = kids[k], t1 = kids[k + 1], t2 = kids[k + 2], t3 = kids[k + 3];
    float v0 = (d < HDIM) ? embed[(size_t)t0 * DDIM + h * HDIM + d] : 0.f;
    float v1 = (d < HDIM) ? embed[(size_t)t1 * DDIM + h * HDIM + d] : 0.f;
    float v2 = (d < HDIM) ? embed[(size_t)t2 * DDIM + h * HDIM + d] : 0.f;
    float v3 = (d < HDIM) ? embed[(size_t)t3 * DDIM + h * HDIM + d] : 0.f;
#pragma unroll
    for (int i = 0; i < NQ; i++) {
      float4 p = P4[((qg + 4 * i) * Lk + k) >> 2];
      acc[i] += p.x * v0 + p.y * v1 + p.z * v2 + p.w * v3;
    }
  }
  float mx = -1e30f;
#pragma unroll
  for (int i = 0; i < NQ; i++) mx = fmaxf(mx, acc[i]);
  __shared__ float red[4][64];
  red[threadIdx.x >> 6][d] = mx;
  __syncthreads();
  if (threadIdx.x < 64 && d < HDIM) {
    float m4 = fmaxf(fmaxf(red[0][d], red[1][d]), fmaxf(red[2][d], red[3][d]));
    att_out[n * DDIM + h * HDIM + d] = m4;
  }
}

// ---------------------------------------------------------------------------
// att_score MLP: sigmoid(relu([adb;abd] @ w1 + b1) @ w2 + b2).  grid=16
__global__ __launch_bounds__(256) void mlp_kernel(
    const float* __restrict__ adb, const float* __restrict__ abd,
    const float* __restrict__ w1, const float* __restrict__ b1,
    const float* __restrict__ w2, const float* __restrict__ b2,
    float* __restrict__ att_score) {
  int n = blockIdx.x;
  float partial = 0.f;
  for (int j = threadIdx.x; j < 300; j += 256) {
    float h = b1[j];
    for (int k = 0; k < 300; k++) h += adb[n * DDIM + k] * w1[k * 300 + j];
    for (int k = 0; k < 300; k++) h += abd[n * DDIM + k] * w1[(300 + k) * 300 + j];
    partial += fmaxf(h, 0.f) * w2[j];
  }
  __shared__ float red[256];
  red[threadIdx.x] = partial;
  __syncthreads();
  for (int s = 128; s > 0; s >>= 1) {
    if (threadIdx.x < s) red[threadIdx.x] += red[threadIdx.x + s];
    __syncthreads();
  }
  if (threadIdx.x == 0) att_score[n] = 1.0f / (1.0f + expf(-(red[0] + b2[0])));
}

// ---------------------------------------------------------------------------
// tok + max over candidates: tokmax[m][t] = max_n cand[m][n].ctx[m][t]. grid=64
__global__ __launch_bounds__(256) void tok_kernel(
    const float* __restrict__ candg,   // [64][16][300]
    const float* __restrict__ ctx2g,   // [64][50][300]
    float* __restrict__ tokmax) {      // [64][50]
  int m = blockIdx.x;
  __shared__ float cand[NN * DDIM];
  __shared__ float ctx[16 * DDIM];
  __shared__ float tokb[NN][17];
  for (int i = threadIdx.x; i < NN * DDIM; i += 256)
    cand[i] = candg[(size_t)m * NN * DDIM + i];
  int nI = threadIdx.x >> 4, tt = threadIdx.x & 15;
  for (int cbase = 0; cbase < CTX_LL; cbase += 16) {
    __syncthreads();
    for (int i = threadIdx.x; i < 16 * DDIM; i += 256) {
      int rr = i / DDIM, cc = i - rr * DDIM;
      int t = cbase + rr;
      ctx[rr * DDIM + cc] = (t < CTX_LL) ? ctx2g[(size_t)(m * CTX_LL + t) * DDIM + cc] : 0.f;
    }
    __syncthreads();
    const float4* ca = (const float4*)(cand + nI * DDIM);
    const float4* cb = (const float4*)(ctx + tt * DDIM);
    float dsum = 0.f;
#pragma unroll
    for (int c = 0; c < 75; c++) {
      float4 a = ca[c], b = cb[c];
      dsum += a.x * b.x + a.y * b.y + a.z * b.z + a.w * b.w;
    }
    tokb[nI][tt] = dsum;
    __syncthreads();
    if (threadIdx.x < 16) {
      float mx = -1e30f;
      for (int nn = 0; nn < NN; nn++) mx = fmaxf(mx, tokb[nn][threadIdx.x]);
      int t = cbase + threadIdx.x;
      if (t < CTX_LL) tokmax[m * CTX_LL + t] = mx;
    }
  }
}

// ---------------------------------------------------------------------------
// p = softmax(tokmax), ctxv = p @ ctx, local_att = cand . ctxv.  grid=64
__global__ __launch_bounds__(256) void ctxv_kernel(
    const float* __restrict__ tokmax,
    const float* __restrict__ ctx2g,
    const float* __restrict__ candg,
    float* __restrict__ local_att) {  // [64][16]
  int m = blockIdx.x, tid = threadIdx.x;
  __shared__ float p[64];
  __shared__ float sctxv[DDIM];
  if (tid < 64) {
    float v = (tid < CTX_LL) ? tokmax[m * CTX_LL + tid] : -1e30f;
    float mx = v;
#pragma unroll
    for (int o = 32; o >= 1; o >>= 1) mx = fmaxf(mx, __shfl_xor(mx, o));
    float e = (tid < CTX_LL) ? expf(v - mx) : 0.f;
    float s = e;
#pragma unroll
    for (int o = 32; o >= 1; o >>= 1) s += __shfl_xor(s, o);
    p[tid] = e / s;
  }
  __syncthreads();
  for (int d = tid; d < DDIM; d += 256) {
    float acc = 0.f;
    for (int t = 0; t < CTX_LL; t++)
      acc += p[t] * ctx2g[(size_t)(m * CTX_LL + t) * DDIM + d];
    sctxv[d] = acc;
  }
  __syncthreads();
  int nI = tid >> 4, j = tid & 15;
  float dd = 0.f;
  for (int i = j; i < DDIM; i += 16)
    dd += candg[(size_t)(m * NN + nI) * DDIM + i] * sctxv[i];
#pragma unroll
  for (int o = 8; o >= 1; o >>= 1) dd += __shfl_xor(dd, o);
  if (j == 0) local_att[m * NN + nI] = dd;
}

// ---------------------------------------------------------------------------
// Final: cosines, feature combine, per-mention standardize/softmax/renorm.
__global__ __launch_bounds__(256) void final_kernel(
    const float* __restrict__ ms,       // [64][768]
    const float* __restrict__ mc2,      // [2][64][768] partial sums
    const float* __restrict__ title,    // [16][768]
    const float* __restrict__ bert,     // [768]
    const float* __restrict__ att_score,// [16]
    const float* __restrict__ m2c_prior,// [16]
    const float* __restrict__ hand,     // [16][1]
    const float* __restrict__ local_att,// [64][16]
    const float* __restrict__ w7,       // [7]
    const float* __restrict__ b7,       // [1]
    float* __restrict__ out) {          // z|sm|u each [64][16]
  int m = blockIdx.x, tid = threadIdx.x;
  __shared__ float sms[FNUM], smc[FNUM], smd[FNUM];
  __shared__ float snorm[3], sscore[16], wred[3][4];
  for (int i = tid; i < FNUM; i += 256) {
    sms[i] = ms[m * FNUM + i];
    smc[i] = (mc2[(size_t)m * FNUM + i] + mc2[(size_t)(MM + m) * FNUM + i]) * (1.0f / 46.0f);
    smd[i] = bert[i];
  }
  __syncthreads();
  float p1 = 0.f, p2 = 0.f, p3 = 0.f;
  for (int i = tid; i < FNUM; i += 256) {
    float a = sms[i], b = smc[i], c = smd[i];
    p1 += a * a; p2 += b * b; p3 += c * c;
  }
#pragma unroll
  for (int o = 32; o >= 1; o >>= 1) {
    p1 += __shfl_xor(p1, o); p2 += __shfl_xor(p2, o); p3 += __shfl_xor(p3, o);
  }
  int wid = tid >> 6, lane = tid & 63;
  if (lane == 0) { wred[0][wid] = p1; wred[1][wid] = p2; wred[2][wid] = p3; }
  __syncthreads();
  if (tid == 0) {
    snorm[0] = fmaxf(sqrtf(wred[0][0] + wred[0][1] + wred[0][2] + wred[0][3]), 1e-6f);
    snorm[1] = fmaxf(sqrtf(wred[1][0] + wred[1][1] + wred[1][2] + wred[1][3]), 1e-6f);
    snorm[2] = fmaxf(sqrtf(wred[2][0] + wred[2][1] + wred[2][2] + wred[2][3]), 1e-6f);
  }
  __syncthreads();
  int nI = tid >> 4, j = tid & 15;
  float d1 = 0.f, d2 = 0.f, d3 = 0.f, d4 = 0.f;
  for (int i = j; i < FNUM; i += 16) {
    float t = title[nI * FNUM + i];
    d1 += sms[i] * t; d2 += smc[i] * t; d3 += smd[i] * t; d4 += t * t;
  }
#pragma unroll
  for (int o = 8; o >= 1; o >>= 1) {
    d1 += __shfl_xor(d1, o); d2 += __shfl_xor(d2, o);
    d3 += __shfl_xor(d3, o); d4 += __shfl_xor(d4, o);
  }
  if (j == 0) {
    float nt = fmaxf(sqrtf(d4), 1e-6f);
    float cos_st = d1 / (snorm[0] * nt);
    float cos_ct = d2 / (snorm[1] * nt);
    float cos_dt = d3 / (snorm[2] * nt);
    float score = hand[nI] * w7[0] + m2c_prior[nI] * w7[1] +
                  local_att[m * NN + nI] * w7[2] + att_score[nI] * w7[3] +
                  cos_st * w7[4] + cos_dt * w7[5] + cos_ct * w7[6] + b7[0];
    sscore[nI] = score;
  }
  __syncthreads();
  if (tid < 16) {
    float x = sscore[tid];
    float s = x;
#pragma unroll
    for (int o = 8; o >= 1; o >>= 1) s += __shfl_xor(s, o);
    float mu = s * (1.0f / 16.0f);
    float dv = (x - mu) * (x - mu);
    float vs = dv;
#pragma unroll
    for (int o = 8; o >= 1; o >>= 1) vs += __shfl_xor(vs, o);
    float sd = sqrtf(vs * (1.0f / 15.0f));  // ddof=1
    float z = (x - mu) / sd;
    float zm = z;
#pragma unroll
    for (int o = 8; o >= 1; o >>= 1) zm = fmaxf(zm, __shfl_xor(zm, o));
    float e = expf(z - zm);
    float es = e;
#pragma unroll
    for (int o = 8; o >= 1; o >>= 1) es += __shfl_xor(es, o);
    float sm = e / es;
    float zmin = z;
#pragma unroll
    for (int o = 8; o >= 1; o >>= 1) zmin = fminf(zmin, __shfl_xor(zmin, o));
    float u0 = (z + 1.0f - zmin) / (zm - zmin);
    float us = u0;
#pragma unroll
    for (int o = 8; o >= 1; o >>= 1) us += __shfl_xor(us, o);
    float u = u0 / us;
    out[m * NN + tid] = z;
    out[MM * NN + m * NN + tid] = sm;
    out[2 * MM * NN + m * NN + tid] = u;
  }
}

// ---------------------------------------------------------------------------
extern "C" void kernel_launch(void* const* d_in, const int* in_sizes, int n_in,
                              void* d_out, int out_size, void* d_ws, size_t ws_size,
                              hipStream_t stream) {
  const int*   mention_vec   = (const int*)d_in[3];
  const int*   context_vec   = (const int*)d_in[4];
  const int*   doc_vec       = (const int*)d_in[5];
  const float* title_vec     = (const float*)d_in[6];
  const int*   body_vec      = (const int*)d_in[7];
  const float* m2c_prior     = (const float*)d_in[9];
  const int*   men2cands     = (const int*)d_in[10];
  const int*   contexts_ids  = (const int*)d_in[11];
  const float* hand_features = (const float*)d_in[12];
  const float* bert_doc_vec  = (const float*)d_in[13];
  const float* embed_table   = (const float*)d_in[14];
  const float* conv_ms_w     = (const float*)d_in[15];
  const float* conv_ms_b     = (const float*)d_in[16];
  const float* conv_mc_w     = (const float*)d_in[17];
  const float* conv_mc_b     = (const float*)d_in[18];
  const float* layer_local_w = (const float*)d_in[19];
  const float* layer_local_b = (const float*)d_in[20];
  const float* att_w1        = (const float*)d_in[21];
  const float* att_b1        = (const float*)d_in[22];
  const float* att_w2        = (const float*)d_in[23];
  const float* att_b2        = (const float*)d_in[24];

  float* ws      = (float*)d_ws;
  float* msg     = ws + OFF_MSG;
  float* ctxg    = ws + OFF_CTXG;
  float* ctx2g   = ws + OFF_CTX2G;
  float* candg   = ws + OFF_CANDG;
  float* ms      = ws + OFF_MS;
  float* mc2     = ws + OFF_MC;
  float* S       = ws + OFF_S;
  float* att_db  = ws + OFF_ADB;
  float* att_bd  = ws + OFF_ABD;
  float* att_sc  = ws + OFF_ASC;
  float* tokmax  = ws + OFF_TOKMAX;
  float* latt    = ws + OFF_LATT;
  float* out     = (float*)d_out;

  gather_kernel<<<dim3(9000), dim3(256), 0, stream>>>(
      embed_table, mention_vec, context_vec, contexts_ids, men2cands, msg);
  conv_ms_kernel<<<dim3(MM), dim3(256), 0, stream>>>(msg, conv_ms_w, conv_ms_b, ms);
  conv_mc_kernel<<<dim3(MM, 2, 3), dim3(256), 0, stream>>>(ctxg, conv_mc_w, conv_mc_b, mc2);
  scores_kernel<0><<<dim3(28, NN), dim3(256), 0, stream>>>(embed_table, doc_vec, body_vec, S);
  scores_kernel<1><<<dim3(28, NN), dim3(256), 0, stream>>>(embed_table, doc_vec, body_vec, S);
  softmax_kernel<<<dim3(6000), dim3(256), 0, stream>>>(S);
  pv_kernel<0><<<dim3(NN, NHEADS), dim3(256), 0, stream>>>(embed_table, doc_vec, body_vec, S, att_db);
  pv_kernel<1><<<dim3(NN, NHEADS), dim3(256), 0, stream>>>(embed_table, doc_vec, body_vec, S, att_bd);
  mlp_kernel<<<dim3(NN), dim3(256), 0, stream>>>(att_db, att_bd, att_w1, att_b1, att_w2, att_b2, att_sc);
  tok_kernel<<<dim3(MM), dim3(256), 0, stream>>>(candg, ctx2g, tokmax);
  ctxv_kernel<<<dim3(MM), dim3(256), 0, stream>>>(tokmax, ctx2g, candg, latt);
  final_kernel<<<dim3(MM), dim3(256), 0, stream>>>(
      ms, mc2, title_vec, bert_doc_vec, att_sc, m2c_prior, hand_features,
      latt, layer_local_w, layer_local_b, out);
}

// Round 2
// 696.703 us; speedup vs baseline: 1.9266x; 1.9266x over previous
//
#include <hip/hip_runtime.h>

#define MM 64
#define NN 16
#define DDIM 300
#define FNUM 768
#define SURF_LL 4
#define CTX_LL 50
#define DOC_LL 100
#define BODY_LL 200
#define NHEADS 5
#define HDIM 60

// ---- workspace layout (float offsets) ----
#define OFF_MSG    0
#define OFF_CTXG   (OFF_MSG + MM*SURF_LL*DDIM)     // mention emb   [64][4][300]
#define OFF_CTX2G  (OFF_CTXG + MM*CTX_LL*DDIM)     // context_vec emb [64][50][300]
#define OFF_CANDG  (OFF_CTX2G + MM*CTX_LL*DDIM)    // contexts_ids emb [64][50][300]
#define OFF_MS     (OFF_CANDG + MM*NN*DDIM)        // cand emb [64][16][300]
#define OFF_MC     (OFF_MS + MM*FNUM)              // ms [64][768]
#define OFF_S      (OFF_MC + 2*MM*FNUM)            // P (softmaxed scores) [160][20000]
#define OFF_PV0    (OFF_S + 160*20000)             // pv partial max dir0 [16][5][7][60]
#define OFF_PV1    (OFF_PV0 + NN*NHEADS*7*HDIM)    // pv partial max dir1 [16][5][5][60]
#define OFF_ASC    (OFF_PV1 + NN*NHEADS*5*HDIM)
#define OFF_TOKMAX (OFF_ASC + 16)
#define OFF_LATT   (OFF_TOKMAX + MM*CTX_LL)
#define WS_FLOATS  (OFF_LATT + MM*NN)

// ---------------------------------------------------------------------------
// Gather all needed embedding rows contiguously into ws.
__global__ __launch_bounds__(256) void gather_kernel(
    const float* __restrict__ embed,
    const int* __restrict__ mention_vec,
    const int* __restrict__ context_vec,
    const int* __restrict__ contexts_ids,
    const int* __restrict__ men2cands,
    float* __restrict__ dst) {
  int e = blockIdx.x * 256 + threadIdx.x;
  int row = e / DDIM;
  int col = e - row * DDIM;
  int tok;
  if (row < 256)       tok = mention_vec[row];
  else if (row < 3456) tok = context_vec[row - 256];
  else if (row < 6656) tok = contexts_ids[row - 3456];
  else                 tok = men2cands[row - 6656];
  dst[e] = embed[(size_t)tok * DDIM + col];
}

// ---------------------------------------------------------------------------
// conv_ms: kernel width 2 over L=4 -> 3 positions, relu, mean.  grid=64
__global__ __launch_bounds__(256) void conv_ms_kernel(
    const float* __restrict__ msg,   // [64][4][300]
    const float* __restrict__ W,     // [768][300][2]
    const float* __restrict__ B,
    float* __restrict__ ms) {        // [64][768]
  int m = blockIdx.x;
  const float* x0 = msg + (m * SURF_LL + 0) * DDIM;
  const float* x1 = msg + (m * SURF_LL + 1) * DDIM;
  const float* x2 = msg + (m * SURF_LL + 2) * DDIM;
  const float* x3 = msg + (m * SURF_LL + 3) * DDIM;
  for (int f = threadIdx.x; f < FNUM; f += 256) {
    const float2* wf = (const float2*)(W + (size_t)f * 600);
    float a0 = 0.f, a1 = 0.f, a2 = 0.f;
    for (int d = 0; d < DDIM; d++) {
      float2 w = wf[d];
      float v0 = x0[d], v1 = x1[d], v2 = x2[d], v3 = x3[d];
      a0 += v0 * w.x + v1 * w.y;
      a1 += v1 * w.x + v2 * w.y;
      a2 += v2 * w.x + v3 * w.y;
    }
    float b = B[f];
    float r = fmaxf(a0 + b, 0.f) + fmaxf(a1 + b, 0.f) + fmaxf(a2 + b, 0.f);
    ms[m * FNUM + f] = r * (1.0f / 3.0f);
  }
}

// ---------------------------------------------------------------------------
// conv_mc: kernel width 5 over L=50 -> 46 positions, relu, partial sums.
__global__ __launch_bounds__(256) void conv_mc_kernel(
    const float* __restrict__ ctxg,  // [64][50][300]
    const float* __restrict__ W,     // [768][300][5]
    const float* __restrict__ B,
    float* __restrict__ mc2) {       // [2][64][768]
  int m = blockIdx.x, th = blockIdx.y, ft = blockIdx.z;
  int f = ft * 256 + threadIdx.x;
  int t0 = th * 23;
  const float* x = ctxg + (size_t)(m * CTX_LL + t0) * DDIM;
  const float* wf = W + (size_t)f * 1500;
  float acc[23];
#pragma unroll
  for (int i = 0; i < 23; i++) acc[i] = 0.f;
  for (int d = 0; d < DDIM; d++) {
    float w0 = wf[d * 5 + 0], w1 = wf[d * 5 + 1], w2 = wf[d * 5 + 2];
    float w3 = wf[d * 5 + 3], w4 = wf[d * 5 + 4];
    float xv[27];
#pragma unroll
    for (int j = 0; j < 27; j++) xv[j] = x[j * DDIM + d];  // uniform -> s_load
#pragma unroll
    for (int t = 0; t < 23; t++)
      acc[t] += xv[t] * w0 + xv[t + 1] * w1 + xv[t + 2] * w2 + xv[t + 3] * w3 +
                xv[t + 4] * w4;
  }
  float b = B[f];
  float s = 0.f;
#pragma unroll
  for (int t = 0; t < 23; t++) s += fmaxf(acc[t] + b, 0.f);
  mc2[(size_t)(th * MM + m) * FNUM + f] = s;
}

// ---------------------------------------------------------------------------
// Fused QK^T + softmax.  Block = (q-tile of 32, n, h).  K rows staged in LDS
// stride 61 (lane-strided reads conflict-free), Q tile in LDS (broadcast).
// Wave w computes 8 q rows; per lane KPL k-columns.  Softmax in-register via
// wave shuffles; normalized P written coalesced to ws.
template <int DIR>
__global__ __launch_bounds__(256) void attn_scores_kernel(
    const float* __restrict__ embed,
    const int* __restrict__ doc_vec,
    const int* __restrict__ body_vec,
    float* __restrict__ P) {
  constexpr int Lq = DIR ? 200 : 100;
  constexpr int Lk = DIR ? 100 : 200;
  constexpr int KPL = DIR ? 2 : 4;
  int qt = blockIdx.x, n = blockIdx.y, h = blockIdx.z;
  const int* qids = DIR ? body_vec + n * BODY_LL : doc_vec;
  const int* kids = DIR ? doc_vec : body_vec + n * BODY_LL;
  __shared__ float Ks[Lk * 61];
  __shared__ float Qs[32 * 61];
  for (int idx = threadIdx.x; idx < Lk * 15; idx += 256) {
    int r = idx / 15, c = idx - r * 15;
    float4 v = *(const float4*)(embed + (size_t)kids[r] * DDIM + h * HDIM + c * 4);
    float* dp = Ks + r * 61 + c * 4;
    dp[0] = v.x; dp[1] = v.y; dp[2] = v.z; dp[3] = v.w;
  }
  for (int idx = threadIdx.x; idx < 32 * 15; idx += 256) {
    int r = idx / 15, c = idx - r * 15;
    int q = qt * 32 + r; if (q >= Lq) q = Lq - 1;
    float4 v = *(const float4*)(embed + (size_t)qids[q] * DDIM + h * HDIM + c * 4);
    float* dp = Qs + r * 61 + c * 4;
    dp[0] = v.x; dp[1] = v.y; dp[2] = v.z; dp[3] = v.w;
  }
  __syncthreads();
  int w = threadIdx.x >> 6, lane = threadIdx.x & 63;
  float acc[8][KPL];
#pragma unroll
  for (int i = 0; i < 8; i++)
#pragma unroll
    for (int j = 0; j < KPL; j++) acc[i][j] = 0.f;
  for (int d = 0; d < HDIM; d++) {
    float kv[KPL];
#pragma unroll
    for (int j = 0; j < KPL; j++) {
      int kk = lane + 64 * j; if (kk >= Lk) kk = Lk - 1;
      kv[j] = Ks[kk * 61 + d];
    }
#pragma unroll
    for (int i = 0; i < 8; i++) {
      float qv = Qs[(w * 8 + i) * 61 + d];
#pragma unroll
      for (int j = 0; j < KPL; j++) acc[i][j] += qv * kv[j];
    }
  }
  const float scale = 0.12909944487358056f;  // 1/sqrt(60)
#pragma unroll
  for (int i = 0; i < 8; i++) {
    int q = qt * 32 + w * 8 + i;
    float mx = -1e30f;
#pragma unroll
    for (int j = 0; j < KPL; j++)
      if (lane + 64 * j < Lk) mx = fmaxf(mx, acc[i][j]);
#pragma unroll
    for (int o = 32; o >= 1; o >>= 1) mx = fmaxf(mx, __shfl_xor(mx, o));
    float mxs = mx * scale;
    float p[KPL];
    float s = 0.f;
#pragma unroll
    for (int j = 0; j < KPL; j++) {
      p[j] = (lane + 64 * j < Lk) ? __expf(acc[i][j] * scale - mxs) : 0.f;
      s += p[j];
    }
#pragma unroll
    for (int o = 32; o >= 1; o >>= 1) s += __shfl_xor(s, o);
    float inv = 1.0f / s;
    if (q < Lq) {
      float* rowp = P + (size_t)((n * 2 + DIR) * NHEADS + h) * 20000 + q * Lk;
#pragma unroll
      for (int j = 0; j < KPL; j++) {
        int kk = lane + 64 * j;
        if (kk < Lk) rowp[kk] = p[j] * inv;
      }
    }
  }
}

// ---------------------------------------------------------------------------
// PV + partial max-pool over q.  Block = (p-tile, n, h).  K in LDS (stride 61,
// lanes<->d so reads lane-consecutive), P tile in LDS as float4 rows.
template <int DIR>
__global__ __launch_bounds__(256) void attn_pv_kernel(
    const float* __restrict__ embed,
    const int* __restrict__ doc_vec,
    const int* __restrict__ body_vec,
    const float* __restrict__ P,
    float* __restrict__ pvpart) {  // [16][5][NPT][60]
  constexpr int Lq = DIR ? 200 : 100;
  constexpr int Lk = DIR ? 100 : 200;
  constexpr int QT = DIR ? 40 : 16;
  constexpr int NPT = DIR ? 5 : 7;
  constexpr int PSTR = Lk + 4;
  int pt = blockIdx.x, n = blockIdx.y, h = blockIdx.z;
  const int* kids = DIR ? doc_vec : body_vec + n * BODY_LL;
  __shared__ float Ks[Lk * 61];
  __shared__ float Pt[QT * PSTR];
  __shared__ float red[4][64];
  for (int idx = threadIdx.x; idx < Lk * 15; idx += 256) {
    int r = idx / 15, c = idx - r * 15;
    float4 v = *(const float4*)(embed + (size_t)kids[r] * DDIM + h * HDIM + c * 4);
    float* dp = Ks + r * 61 + c * 4;
    dp[0] = v.x; dp[1] = v.y; dp[2] = v.z; dp[3] = v.w;
  }
  const float* Prow = P + (size_t)((n * 2 + DIR) * NHEADS + h) * 20000;
  for (int idx = threadIdx.x; idx < QT * (Lk / 4); idx += 256) {
    int r = idx / (Lk / 4), c = idx - r * (Lk / 4);
    int q = pt * QT + r; if (q >= Lq) q = Lq - 1;
    float4 v = *(const float4*)(Prow + q * Lk + c * 4);
    *(float4*)(Pt + r * PSTR + c * 4) = v;
  }
  __syncthreads();
  int w = threadIdx.x >> 6, lane = threadIdx.x & 63;
  float omax = -1e30f;
#pragma unroll
  for (int i = 0; i < QT / 4; i++) {
    int r = w + 4 * i;
    int q = pt * QT + r;
    float o = 0.f;
    for (int k = 0; k < Lk; k += 4) {
      float4 p = *(const float4*)(Pt + r * PSTR + k);
      o += p.x * Ks[k * 61 + lane] + p.y * Ks[(k + 1) * 61 + lane] +
           p.z * Ks[(k + 2) * 61 + lane] + p.w * Ks[(k + 3) * 61 + lane];
    }
    if (q < Lq) omax = fmaxf(omax, o);
  }
  red[w][lane] = omax;
  __syncthreads();
  if (threadIdx.x < 64 && lane < HDIM) {
    float m4 = fmaxf(fmaxf(red[0][lane], red[1][lane]),
                     fmaxf(red[2][lane], red[3][lane]));
    pvpart[(size_t)(((n * NHEADS + h) * NPT) + pt) * HDIM + lane] = m4;
  }
}

// ---------------------------------------------------------------------------
// Combine pv partials (max over tiles) into comb[600] in LDS, then MLP:
// sigmoid(relu(comb @ w1 + b1) @ w2 + b2).  grid=16
__global__ __launch_bounds__(256) void mlp_kernel(
    const float* __restrict__ pv0, const float* __restrict__ pv1,
    const float* __restrict__ w1, const float* __restrict__ b1,
    const float* __restrict__ w2, const float* __restrict__ b2,
    float* __restrict__ att_score) {
  int n = blockIdx.x, tid = threadIdx.x;
  __shared__ float comb[600];
  for (int idx = tid; idx < 300; idx += 256) {
    int h = idx / 60, d = idx - h * 60;
    float mx = -1e30f;
#pragma unroll
    for (int pt = 0; pt < 7; pt++)
      mx = fmaxf(mx, pv0[(size_t)((n * NHEADS + h) * 7 + pt) * HDIM + d]);
    comb[idx] = mx;
    mx = -1e30f;
#pragma unroll
    for (int pt = 0; pt < 5; pt++)
      mx = fmaxf(mx, pv1[(size_t)((n * NHEADS + h) * 5 + pt) * HDIM + d]);
    comb[300 + idx] = mx;
  }
  __syncthreads();
  float partial = 0.f;
  for (int j = tid; j < 300; j += 256) {
    float hh = b1[j];
    for (int k = 0; k < 600; k++) hh += comb[k] * w1[k * 300 + j];
    partial += fmaxf(hh, 0.f) * w2[j];
  }
  __shared__ float redd[256];
  redd[tid] = partial;
  __syncthreads();
  for (int s = 128; s > 0; s >>= 1) {
    if (tid < s) redd[tid] += redd[tid + s];
    __syncthreads();
  }
  if (tid == 0) att_score[n] = 1.0f / (1.0f + expf(-(redd[0] + b2[0])));
}

// ---------------------------------------------------------------------------
// tok + max over candidates: tokmax[m][t] = max_n cand[m][n].ctx[m][t]. grid=64
__global__ __launch_bounds__(256) void tok_kernel(
    const float* __restrict__ candg,   // [64][16][300]
    const float* __restrict__ ctx2g,   // [64][50][300]
    float* __restrict__ tokmax) {      // [64][50]
  int m = blockIdx.x;
  __shared__ float cand[NN * DDIM];
  __shared__ float ctx[16 * DDIM];
  __shared__ float tokb[NN][17];
  for (int i = threadIdx.x; i < NN * DDIM; i += 256)
    cand[i] = candg[(size_t)m * NN * DDIM + i];
  int nI = threadIdx.x >> 4, tt = threadIdx.x & 15;
  for (int cbase = 0; cbase < CTX_LL; cbase += 16) {
    __syncthreads();
    for (int i = threadIdx.x; i < 16 * DDIM; i += 256) {
      int rr = i / DDIM, cc = i - rr * DDIM;
      int t = cbase + rr;
      ctx[rr * DDIM + cc] = (t < CTX_LL) ? ctx2g[(size_t)(m * CTX_LL + t) * DDIM + cc] : 0.f;
    }
    __syncthreads();
    const float4* ca = (const float4*)(cand + nI * DDIM);
    const float4* cb = (const float4*)(ctx + tt * DDIM);
    float dsum = 0.f;
#pragma unroll
    for (int c = 0; c < 75; c++) {
      float4 a = ca[c], b = cb[c];
      dsum += a.x * b.x + a.y * b.y + a.z * b.z + a.w * b.w;
    }
    tokb[nI][tt] = dsum;
    __syncthreads();
    if (threadIdx.x < 16) {
      float mx = -1e30f;
      for (int nn = 0; nn < NN; nn++) mx = fmaxf(mx, tokb[nn][threadIdx.x]);
      int t = cbase + threadIdx.x;
      if (t < CTX_LL) tokmax[m * CTX_LL + t] = mx;
    }
  }
}

// ---------------------------------------------------------------------------
// p = softmax(tokmax), ctxv = p @ ctx, local_att = cand . ctxv.  grid=64
__global__ __launch_bounds__(256) void ctxv_kernel(
    const float* __restrict__ tokmax,
    const float* __restrict__ ctx2g,
    const float* __restrict__ candg,
    float* __restrict__ local_att) {  // [64][16]
  int m = blockIdx.x, tid = threadIdx.x;
  __shared__ float p[64];
  __shared__ float sctxv[DDIM];
  if (tid < 64) {
    float v = (tid < CTX_LL) ? tokmax[m * CTX_LL + tid] : -1e30f;
    float mx = v;
#pragma unroll
    for (int o = 32; o >= 1; o >>= 1) mx = fmaxf(mx, __shfl_xor(mx, o));
    float e = (tid < CTX_LL) ? expf(v - mx) : 0.f;
    float s = e;
#pragma unroll
    for (int o = 32; o >= 1; o >>= 1) s += __shfl_xor(s, o);
    p[tid] = e / s;
  }
  __syncthreads();
  for (int d = tid; d < DDIM; d += 256) {
    float acc = 0.f;
    for (int t = 0; t < CTX_LL; t++)
      acc += p[t] * ctx2g[(size_t)(m * CTX_LL + t) * DDIM + d];
    sctxv[d] = acc;
  }
  __syncthreads();
  int nI = tid >> 4, j = tid & 15;
  float dd = 0.f;
  for (int i = j; i < DDIM; i += 16)
    dd += candg[(size_t)(m * NN + nI) * DDIM + i] * sctxv[i];
#pragma unroll
  for (int o = 8; o >= 1; o >>= 1) dd += __shfl_xor(dd, o);
  if (j == 0) local_att[m * NN + nI] = dd;
}

// ---------------------------------------------------------------------------
// Final: cosines, feature combine, per-mention standardize/softmax/renorm.
__global__ __launch_bounds__(256) void final_kernel(
    const float* __restrict__ ms,       // [64][768]
    const float* __restrict__ mc2,      // [2][64][768] partial sums
    const float* __restrict__ title,    // [16][768]
    const float* __restrict__ bert,     // [768]
    const float* __restrict__ att_score,// [16]
    const float* __restrict__ m2c_prior,// [16]
    const float* __restrict__ hand,     // [16][1]
    const float* __restrict__ local_att,// [64][16]
    const float* __restrict__ w7,       // [7]
    const float* __restrict__ b7,       // [1]
    float* __restrict__ out) {          // z|sm|u each [64][16]
  int m = blockIdx.x, tid = threadIdx.x;
  __shared__ float sms[FNUM], smc[FNUM], smd[FNUM];
  __shared__ float snorm[3], sscore[16], wred[3][4];
  for (int i = tid; i < FNUM; i += 256) {
    sms[i] = ms[m * FNUM + i];
    smc[i] = (mc2[(size_t)m * FNUM + i] + mc2[(size_t)(MM + m) * FNUM + i]) * (1.0f / 46.0f);
    smd[i] = bert[i];
  }
  __syncthreads();
  float p1 = 0.f, p2 = 0.f, p3 = 0.f;
  for (int i = tid; i < FNUM; i += 256) {
    float a = sms[i], b = smc[i], c = smd[i];
    p1 += a * a; p2 += b * b; p3 += c * c;
  }
#pragma unroll
  for (int o = 32; o >= 1; o >>= 1) {
    p1 += __shfl_xor(p1, o); p2 += __shfl_xor(p2, o); p3 += __shfl_xor(p3, o);
  }
  int wid = tid >> 6, lane = tid & 63;
  if (lane == 0) { wred[0][wid] = p1; wred[1][wid] = p2; wred[2][wid] = p3; }
  __syncthreads();
  if (tid == 0) {
    snorm[0] = fmaxf(sqrtf(wred[0][0] + wred[0][1] + wred[0][2] + wred[0][3]), 1e-6f);
    snorm[1] = fmaxf(sqrtf(wred[1][0] + wred[1][1] + wred[1][2] + wred[1][3]), 1e-6f);
    snorm[2] = fmaxf(sqrtf(wred[2][0] + wred[2][1] + wred[2][2] + wred[2][3]), 1e-6f);
  }
  __syncthreads();
  int nI = tid >> 4, j = tid & 15;
  float d1 = 0.f, d2 = 0.f, d3 = 0.f, d4 = 0.f;
  for (int i = j; i < FNUM; i += 16) {
    float t = title[nI * FNUM + i];
    d1 += sms[i] * t; d2 += smc[i] * t; d3 += smd[i] * t; d4 += t * t;
  }
#pragma unroll
  for (int o = 8; o >= 1; o >>= 1) {
    d1 += __shfl_xor(d1, o); d2 += __shfl_xor(d2, o);
    d3 += __shfl_xor(d3, o); d4 += __shfl_xor(d4, o);
  }
  if (j == 0) {
    float nt = fmaxf(sqrtf(d4), 1e-6f);
    float cos_st = d1 / (snorm[0] * nt);
    float cos_ct = d2 / (snorm[1] * nt);
    float cos_dt = d3 / (snorm[2] * nt);
    float score = hand[nI] * w7[0] + m2c_prior[nI] * w7[1] +
                  local_att[m * NN + nI] * w7[2] + att_score[nI] * w7[3] +
                  cos_st * w7[4] + cos_dt * w7[5] + cos_ct * w7[6] + b7[0];
    sscore[nI] = score;
  }
  __syncthreads();
  if (tid < 16) {
    float x = sscore[tid];
    float s = x;
#pragma unroll
    for (int o = 8; o >= 1; o >>= 1) s += __shfl_xor(s, o);
    float mu = s * (1.0f / 16.0f);
    float dv = (x - mu) * (x - mu);
    float vs = dv;
#pragma unroll
    for (int o = 8; o >= 1; o >>= 1) vs += __shfl_xor(vs, o);
    float sd = sqrtf(vs * (1.0f / 15.0f));  // ddof=1
    float z = (x - mu) / sd;
    float zm = z;
#pragma unroll
    for (int o = 8; o >= 1; o >>= 1) zm = fmaxf(zm, __shfl_xor(zm, o));
    float e = expf(z - zm);
    float es = e;
#pragma unroll
    for (int o = 8; o >= 1; o >>= 1) es += __shfl_xor(es, o);
    float sm = e / es;
    float zmin = z;
#pragma unroll
    for (int o = 8; o >= 1; o >>= 1) zmin = fminf(zmin, __shfl_xor(zmin, o));
    float u0 = (z + 1.0f - zmin) / (zm - zmin);
    float us = u0;
#pragma unroll
    for (int o = 8; o >= 1; o >>= 1) us += __shfl_xor(us, o);
    float u = u0 / us;
    out[m * NN + tid] = z;
    out[MM * NN + m * NN + tid] = sm;
    out[2 * MM * NN + m * NN + tid] = u;
  }
}

// ---------------------------------------------------------------------------
extern "C" void kernel_launch(void* const* d_in, const int* in_sizes, int n_in,
                              void* d_out, int out_size, void* d_ws, size_t ws_size,
                              hipStream_t stream) {
  const int*   mention_vec   = (const int*)d_in[3];
  const int*   context_vec   = (const int*)d_in[4];
  const int*   doc_vec       = (const int*)d_in[5];
  const float* title_vec     = (const float*)d_in[6];
  const int*   body_vec      = (const int*)d_in[7];
  const float* m2c_prior     = (const float*)d_in[9];
  const int*   men2cands     = (const int*)d_in[10];
  const int*   contexts_ids  = (const int*)d_in[11];
  const float* hand_features = (const float*)d_in[12];
  const float* bert_doc_vec  = (const float*)d_in[13];
  const float* embed_table   = (const float*)d_in[14];
  const float* conv_ms_w     = (const float*)d_in[15];
  const float* conv_ms_b     = (const float*)d_in[16];
  const float* conv_mc_w     = (const float*)d_in[17];
  const float* conv_mc_b     = (const float*)d_in[18];
  const float* layer_local_w = (const float*)d_in[19];
  const float* layer_local_b = (const float*)d_in[20];
  const float* att_w1        = (const float*)d_in[21];
  const float* att_b1        = (const float*)d_in[22];
  const float* att_w2        = (const float*)d_in[23];
  const float* att_b2        = (const float*)d_in[24];

  float* ws      = (float*)d_ws;
  float* msg     = ws + OFF_MSG;
  float* ctxg    = ws + OFF_CTXG;
  float* ctx2g   = ws + OFF_CTX2G;
  float* candg   = ws + OFF_CANDG;
  float* ms      = ws + OFF_MS;
  float* mc2     = ws + OFF_MC;
  float* P       = ws + OFF_S;
  float* pv0     = ws + OFF_PV0;
  float* pv1     = ws + OFF_PV1;
  float* att_sc  = ws + OFF_ASC;
  float* tokmax  = ws + OFF_TOKMAX;
  float* latt    = ws + OFF_LATT;
  float* out     = (float*)d_out;

  gather_kernel<<<dim3(9000), dim3(256), 0, stream>>>(
      embed_table, mention_vec, context_vec, contexts_ids, men2cands, msg);
  conv_ms_kernel<<<dim3(MM), dim3(256), 0, stream>>>(msg, conv_ms_w, conv_ms_b, ms);
  conv_mc_kernel<<<dim3(MM, 2, 3), dim3(256), 0, stream>>>(ctxg, conv_mc_w, conv_mc_b, mc2);
  attn_scores_kernel<0><<<dim3(4, NN, NHEADS), dim3(256), 0, stream>>>(
      embed_table, doc_vec, body_vec, P);
  attn_scores_kernel<1><<<dim3(7, NN, NHEADS), dim3(256), 0, stream>>>(
      embed_table, doc_vec, body_vec, P);
  attn_pv_kernel<0><<<dim3(7, NN, NHEADS), dim3(256), 0, stream>>>(
      embed_table, doc_vec, body_vec, P, pv0);
  attn_pv_kernel<1><<<dim3(5, NN, NHEADS), dim3(256), 0, stream>>>(
      embed_table, doc_vec, body_vec, P, pv1);
  mlp_kernel<<<dim3(NN), dim3(256), 0, stream>>>(pv0, pv1, att_w1, att_b1, att_w2, att_b2, att_sc);
  tok_kernel<<<dim3(MM), dim3(256), 0, stream>>>(candg, ctx2g, tokmax);
  ctxv_kernel<<<dim3(MM), dim3(256), 0, stream>>>(tokmax, ctx2g, candg, latt);
  final_kernel<<<dim3(MM), dim3(256), 0, stream>>>(
      ms, mc2, title_vec, bert_doc_vec, att_sc, m2c_prior, hand_features,
      latt, layer_local_w, layer_local_b, out);
}

// Round 3
// 497.458 us; speedup vs baseline: 2.6983x; 1.4005x over previous
//
#include <hip/hip_runtime.h>

#define MM 64
#define NN 16
#define DDIM 300
#define FNUM 768
#define SURF_LL 4
#define CTX_LL 50
#define DOC_LL 100
#define BODY_LL 200
#define NHEADS 5
#define HDIM 60

// GEMM dims for conv_mc:  C[GM][GN] = A[GM][GK] * B^T, K padded 1500->1536
#define GM 2944   // 64 m * 46 t
#define GK 1536
#define GN 768

typedef unsigned short u16;
typedef unsigned int u32;
typedef __attribute__((ext_vector_type(8))) short short8;
typedef __attribute__((ext_vector_type(4))) float f32x4;

// ---- workspace layout (float offsets) ----
#define OFF_MSG    0
#define OFF_CTXG   (OFF_MSG + MM*SURF_LL*DDIM)     // context_vec emb [64][50][300]
#define OFF_CTX2G  (OFF_CTXG + MM*CTX_LL*DDIM)     // contexts_ids emb [64][50][300]
#define OFF_CANDG  (OFF_CTX2G + MM*CTX_LL*DDIM)    // cand emb [64][16][300]
#define OFF_MS     (OFF_CANDG + MM*NN*DDIM)        // ms [64][768]
#define OFF_MC     (OFF_MS + MM*FNUM)              // mc [64][768] (meaned)
#define OFF_PV0    (OFF_MC + MM*FNUM)
#define OFF_PV1    (OFF_PV0 + NN*NHEADS*7*HDIM)
#define OFF_ASC    (OFF_PV1 + NN*NHEADS*5*HDIM)
#define OFF_TOKMAX (OFF_ASC + 16)
#define OFF_LATT   (OFF_TOKMAX + MM*CTX_LL)
#define OFF_X      ((OFF_LATT + MM*NN + 15) & ~15)
// scratch region X (reused across phases; stream is serial):
#define OFF_ABF    OFF_X                   // u16[GM*GK]   (GM*GK/2 floats)
#define OFF_WTMC   (OFF_ABF + GM*GK/2)     // u16[GN*GK]   (GN*GK/2 floats)
#define OFF_WTMS   (OFF_WTMC + GN*GK/2)    // float[600*768]
#define OFF_CRELU  (OFF_WTMS + 600*768)    // float[GM*GN]
#define OFF_P      OFF_X                   // attn P [160][20000] aliases conv scratch

__device__ __forceinline__ u16 f2bf(float x) {
  union { float f; u32 u; } v; v.f = x;
  u32 r = v.u + 0x7FFFu + ((v.u >> 16) & 1u);
  return (u16)(r >> 16);
}

// ---------------------------------------------------------------------------
// Gather all needed embedding rows contiguously into ws.
__global__ __launch_bounds__(256) void gather_kernel(
    const float* __restrict__ embed,
    const int* __restrict__ mention_vec,
    const int* __restrict__ context_vec,
    const int* __restrict__ contexts_ids,
    const int* __restrict__ men2cands,
    float* __restrict__ dst) {
  int e = blockIdx.x * 256 + threadIdx.x;
  int row = e / DDIM;
  int col = e - row * DDIM;
  int tok;
  if (row < 256)       tok = mention_vec[row];
  else if (row < 3456) tok = context_vec[row - 256];
  else if (row < 6656) tok = contexts_ids[row - 3456];
  else                 tok = men2cands[row - 6656];
  dst[e] = embed[(size_t)tok * DDIM + col];
}

// ---------------------------------------------------------------------------
// im2col A build: A_bf[r=(m,t)][k=tap*300+d] = bf16(ctxg[m][t+tap][d]); k>=1500 -> 0
__global__ __launch_bounds__(256) void abuild_kernel(
    const float* __restrict__ ctxg, u32* __restrict__ Abf) {
  int idx = blockIdx.x * 256 + threadIdx.x;  // one u32 = 2 bf16
  int r = idx / (GK / 2);
  int kp = idx - r * (GK / 2);
  int k = kp * 2;
  int m = r / 46, t = r - m * 46;
  u32 out = 0;
#pragma unroll
  for (int j = 0; j < 2; j++) {
    int kj = k + j;
    u16 h = 0;
    if (kj < 1500) {
      int tap = kj / 300;
      int d = kj - tap * 300;
      h = f2bf(ctxg[(size_t)(m * CTX_LL + t + tap) * DDIM + d]);
    }
    out |= (u32)h << (16 * j);
  }
  Abf[idx] = out;
}

// ---------------------------------------------------------------------------
// W repack (n-major): WT[n][k=tap*300+d] = bf16(W[n][d][tap]); k>=1500 -> 0
__global__ __launch_bounds__(256) void wtmc_kernel(
    const float* __restrict__ W, u32* __restrict__ WT) {
  int idx = blockIdx.x * 256 + threadIdx.x;
  int n = idx / (GK / 2);
  int kp = idx - n * (GK / 2);
  int k = kp * 2;
  u32 out = 0;
#pragma unroll
  for (int j = 0; j < 2; j++) {
    int kj = k + j;
    u16 h = 0;
    if (kj < 1500) {
      int tap = kj / 300;
      int d = kj - tap * 300;
      h = f2bf(W[(size_t)n * 1500 + d * 5 + tap]);
    }
    out |= (u32)h << (16 * j);
  }
  WT[idx] = out;
}

// ---------------------------------------------------------------------------
// conv_ms weight transpose: WT[k=d*2+tap][f] = W[f][k]  (fp32)
__global__ __launch_bounds__(256) void wtms_kernel(
    const float* __restrict__ W, float* __restrict__ WT) {
  int idx = blockIdx.x * 256 + threadIdx.x;  // 600*768
  int k = idx / FNUM;
  int f = idx - k * FNUM;
  WT[idx] = W[(size_t)f * 600 + k];
}

// ---------------------------------------------------------------------------
// bf16 MFMA GEMM: Crelu[r][n] = relu(sum_k A[r][k]*WT[n][k] + bias[n])
// 64x64 tile, BK=64, 4 waves as 2x2, each wave 2x2 frags of 16x16x32.
__global__ __launch_bounds__(256) void conv_gemm_kernel(
    const u16* __restrict__ A,    // [GM][GK] bf16
    const u16* __restrict__ B,    // [GN][GK] bf16 (n-major)
    const float* __restrict__ bias,
    float* __restrict__ C) {
  int bm = blockIdx.x, bn = blockIdx.y;
  __shared__ u16 As[64][72];
  __shared__ u16 Bs[64][72];
  int tid = threadIdx.x;
  int w = tid >> 6, lane = tid & 63;
  int wr = w >> 1, wc = w & 1;
  int lg = lane >> 4, lm = lane & 15;
  f32x4 acc[2][2];
#pragma unroll
  for (int i = 0; i < 2; i++)
#pragma unroll
    for (int j = 0; j < 2; j++) acc[i][j] = (f32x4)0.f;
  int c0row = tid >> 3, ck = (tid & 7) * 8;  // 16B chunk per thread, rows 0..31 / 32..63
  const u16* Ag = A + (size_t)(bm * 64) * GK;
  const u16* Bg = B + (size_t)(bn * 64) * GK;
  for (int kt = 0; kt < GK / 64; kt++) {
    int k0 = kt * 64;
    uint4 av0 = *(const uint4*)(Ag + (size_t)c0row * GK + k0 + ck);
    uint4 av1 = *(const uint4*)(Ag + (size_t)(c0row + 32) * GK + k0 + ck);
    uint4 bv0 = *(const uint4*)(Bg + (size_t)c0row * GK + k0 + ck);
    uint4 bv1 = *(const uint4*)(Bg + (size_t)(c0row + 32) * GK + k0 + ck);
    __syncthreads();
    *(uint4*)&As[c0row][ck] = av0;
    *(uint4*)&As[c0row + 32][ck] = av1;
    *(uint4*)&Bs[c0row][ck] = bv0;
    *(uint4*)&Bs[c0row + 32][ck] = bv1;
    __syncthreads();
#pragma unroll
    for (int kk = 0; kk < 2; kk++) {
      short8 af0 = *(const short8*)&As[wr * 32 + lm][kk * 32 + lg * 8];
      short8 af1 = *(const short8*)&As[wr * 32 + 16 + lm][kk * 32 + lg * 8];
      short8 bf0 = *(const short8*)&Bs[wc * 32 + lm][kk * 32 + lg * 8];
      short8 bf1 = *(const short8*)&Bs[wc * 32 + 16 + lm][kk * 32 + lg * 8];
      acc[0][0] = __builtin_amdgcn_mfma_f32_16x16x32_bf16(af0, bf0, acc[0][0], 0, 0, 0);
      acc[0][1] = __builtin_amdgcn_mfma_f32_16x16x32_bf16(af0, bf1, acc[0][1], 0, 0, 0);
      acc[1][0] = __builtin_amdgcn_mfma_f32_16x16x32_bf16(af1, bf0, acc[1][0], 0, 0, 0);
      acc[1][1] = __builtin_amdgcn_mfma_f32_16x16x32_bf16(af1, bf1, acc[1][1], 0, 0, 0);
    }
  }
#pragma unroll
  for (int mf = 0; mf < 2; mf++)
#pragma unroll
    for (int nf = 0; nf < 2; nf++) {
      int col = bn * 64 + wc * 32 + nf * 16 + lm;
      float bb = bias[col];
#pragma unroll
      for (int r = 0; r < 4; r++) {
        int row = bm * 64 + wr * 32 + mf * 16 + lg * 4 + r;
        C[(size_t)row * GN + col] = fmaxf(acc[mf][nf][r] + bb, 0.f);
      }
    }
}

// ---------------------------------------------------------------------------
// mean over 46 positions: mc[m][f] = (1/46) sum_t Crelu[m*46+t][f]
__global__ __launch_bounds__(256) void conv_mean_kernel(
    const float* __restrict__ C, float* __restrict__ mc) {
  int m = blockIdx.x;
  int f = blockIdx.y * 256 + threadIdx.x;
  float s = 0.f;
  for (int t = 0; t < 46; t++) s += C[(size_t)(m * 46 + t) * GN + f];
  mc[m * FNUM + f] = s * (1.0f / 46.0f);
}

// ---------------------------------------------------------------------------
// conv_ms v2: transposed weights (coalesced).  grid=64
__global__ __launch_bounds__(256) void conv_ms_kernel(
    const float* __restrict__ msg,   // [64][4][300]
    const float* __restrict__ WT,    // [600][768]
    const float* __restrict__ B,
    float* __restrict__ ms) {        // [64][768]
  int m = blockIdx.x;
  const float* x = msg + m * SURF_LL * DDIM;
  float a[3][3];
#pragma unroll
  for (int i = 0; i < 3; i++)
#pragma unroll
    for (int j = 0; j < 3; j++) a[i][j] = 0.f;
  int f0 = threadIdx.x;
  for (int d = 0; d < DDIM; d++) {
    float v0 = x[d], v1 = x[DDIM + d], v2 = x[2 * DDIM + d], v3 = x[3 * DDIM + d];
#pragma unroll
    for (int fi = 0; fi < 3; fi++) {
      float wA = WT[(size_t)(2 * d) * FNUM + f0 + fi * 256];
      float wB = WT[(size_t)(2 * d + 1) * FNUM + f0 + fi * 256];
      a[fi][0] += v0 * wA + v1 * wB;
      a[fi][1] += v1 * wA + v2 * wB;
      a[fi][2] += v2 * wA + v3 * wB;
    }
  }
#pragma unroll
  for (int fi = 0; fi < 3; fi++) {
    int f = f0 + fi * 256;
    float b = B[f];
    float r = fmaxf(a[fi][0] + b, 0.f) + fmaxf(a[fi][1] + b, 0.f) +
              fmaxf(a[fi][2] + b, 0.f);
    ms[m * FNUM + f] = r * (1.0f / 3.0f);
  }
}

// ---------------------------------------------------------------------------
// Fused QK^T + softmax.  Block = (q-tile of 32, n, h).
template <int DIR>
__global__ __launch_bounds__(256) void attn_scores_kernel(
    const float* __restrict__ embed,
    const int* __restrict__ doc_vec,
    const int* __restrict__ body_vec,
    float* __restrict__ P) {
  constexpr int Lq = DIR ? 200 : 100;
  constexpr int Lk = DIR ? 100 : 200;
  constexpr int KPL = DIR ? 2 : 4;
  int qt = blockIdx.x, n = blockIdx.y, h = blockIdx.z;
  const int* qids = DIR ? body_vec + n * BODY_LL : doc_vec;
  const int* kids = DIR ? doc_vec : body_vec + n * BODY_LL;
  __shared__ float Ks[Lk * 61];
  __shared__ float Qs[32 * 61];
  for (int idx = threadIdx.x; idx < Lk * 15; idx += 256) {
    int r = idx / 15, c = idx - r * 15;
    float4 v = *(const float4*)(embed + (size_t)kids[r] * DDIM + h * HDIM + c * 4);
    float* dp = Ks + r * 61 + c * 4;
    dp[0] = v.x; dp[1] = v.y; dp[2] = v.z; dp[3] = v.w;
  }
  for (int idx = threadIdx.x; idx < 32 * 15; idx += 256) {
    int r = idx / 15, c = idx - r * 15;
    int q = qt * 32 + r; if (q >= Lq) q = Lq - 1;
    float4 v = *(const float4*)(embed + (size_t)qids[q] * DDIM + h * HDIM + c * 4);
    float* dp = Qs + r * 61 + c * 4;
    dp[0] = v.x; dp[1] = v.y; dp[2] = v.z; dp[3] = v.w;
  }
  __syncthreads();
  int w = threadIdx.x >> 6, lane = threadIdx.x & 63;
  float acc[8][KPL];
#pragma unroll
  for (int i = 0; i < 8; i++)
#pragma unroll
    for (int j = 0; j < KPL; j++) acc[i][j] = 0.f;
  for (int d = 0; d < HDIM; d++) {
    float kv[KPL];
#pragma unroll
    for (int j = 0; j < KPL; j++) {
      int kk = lane + 64 * j; if (kk >= Lk) kk = Lk - 1;
      kv[j] = Ks[kk * 61 + d];
    }
#pragma unroll
    for (int i = 0; i < 8; i++) {
      float qv = Qs[(w * 8 + i) * 61 + d];
#pragma unroll
      for (int j = 0; j < KPL; j++) acc[i][j] += qv * kv[j];
    }
  }
  const float scale = 0.12909944487358056f;  // 1/sqrt(60)
#pragma unroll
  for (int i = 0; i < 8; i++) {
    int q = qt * 32 + w * 8 + i;
    float mx = -1e30f;
#pragma unroll
    for (int j = 0; j < KPL; j++)
      if (lane + 64 * j < Lk) mx = fmaxf(mx, acc[i][j]);
#pragma unroll
    for (int o = 32; o >= 1; o >>= 1) mx = fmaxf(mx, __shfl_xor(mx, o));
    float mxs = mx * scale;
    float p[KPL];
    float s = 0.f;
#pragma unroll
    for (int j = 0; j < KPL; j++) {
      p[j] = (lane + 64 * j < Lk) ? __expf(acc[i][j] * scale - mxs) : 0.f;
      s += p[j];
    }
#pragma unroll
    for (int o = 32; o >= 1; o >>= 1) s += __shfl_xor(s, o);
    float inv = 1.0f / s;
    if (q < Lq) {
      float* rowp = P + (size_t)((n * 2 + DIR) * NHEADS + h) * 20000 + q * Lk;
#pragma unroll
      for (int j = 0; j < KPL; j++) {
        int kk = lane + 64 * j;
        if (kk < Lk) rowp[kk] = p[j] * inv;
      }
    }
  }
}

// ---------------------------------------------------------------------------
// PV + partial max-pool over q.
template <int DIR>
__global__ __launch_bounds__(256) void attn_pv_kernel(
    const float* __restrict__ embed,
    const int* __restrict__ doc_vec,
    const int* __restrict__ body_vec,
    const float* __restrict__ P,
    float* __restrict__ pvpart) {
  constexpr int Lq = DIR ? 200 : 100;
  constexpr int Lk = DIR ? 100 : 200;
  constexpr int QT = DIR ? 40 : 16;
  constexpr int NPT = DIR ? 5 : 7;
  constexpr int PSTR = Lk + 4;
  int pt = blockIdx.x, n = blockIdx.y, h = blockIdx.z;
  const int* kids = DIR ? doc_vec : body_vec + n * BODY_LL;
  __shared__ float Ks[Lk * 61];
  __shared__ float Pt[QT * PSTR];
  __shared__ float red[4][64];
  for (int idx = threadIdx.x; idx < Lk * 15; idx += 256) {
    int r = idx / 15, c = idx - r * 15;
    float4 v = *(const float4*)(embed + (size_t)kids[r] * DDIM + h * HDIM + c * 4);
    float* dp = Ks + r * 61 + c * 4;
    dp[0] = v.x; dp[1] = v.y; dp[2] = v.z; dp[3] = v.w;
  }
  const float* Prow = P + (size_t)((n * 2 + DIR) * NHEADS + h) * 20000;
  for (int idx = threadIdx.x; idx < QT * (Lk / 4); idx += 256) {
    int r = idx / (Lk / 4), c = idx - r * (Lk / 4);
    int q = pt * QT + r; if (q >= Lq) q = Lq - 1;
    float4 v = *(const float4*)(Prow + q * Lk + c * 4);
    *(float4*)(Pt + r * PSTR + c * 4) = v;
  }
  __syncthreads();
  int w = threadIdx.x >> 6, lane = threadIdx.x & 63;
  float omax = -1e30f;
#pragma unroll
  for (int i = 0; i < QT / 4; i++) {
    int r = w + 4 * i;
    int q = pt * QT + r;
    float o = 0.f;
    for (int k = 0; k < Lk; k += 4) {
      float4 p = *(const float4*)(Pt + r * PSTR + k);
      o += p.x * Ks[k * 61 + lane] + p.y * Ks[(k + 1) * 61 + lane] +
           p.z * Ks[(k + 2) * 61 + lane] + p.w * Ks[(k + 3) * 61 + lane];
    }
    if (q < Lq) omax = fmaxf(omax, o);
  }
  red[w][lane] = omax;
  __syncthreads();
  if (threadIdx.x < 64 && lane < HDIM) {
    float m4 = fmaxf(fmaxf(red[0][lane], red[1][lane]),
                     fmaxf(red[2][lane], red[3][lane]));
    pvpart[(size_t)(((n * NHEADS + h) * NPT) + pt) * HDIM + lane] = m4;
  }
}

// ---------------------------------------------------------------------------
__global__ __launch_bounds__(256) void mlp_kernel(
    const float* __restrict__ pv0, const float* __restrict__ pv1,
    const float* __restrict__ w1, const float* __restrict__ b1,
    const float* __restrict__ w2, const float* __restrict__ b2,
    float* __restrict__ att_score) {
  int n = blockIdx.x, tid = threadIdx.x;
  __shared__ float comb[600];
  for (int idx = tid; idx < 300; idx += 256) {
    int h = idx / 60, d = idx - h * 60;
    float mx = -1e30f;
#pragma unroll
    for (int pt = 0; pt < 7; pt++)
      mx = fmaxf(mx, pv0[(size_t)((n * NHEADS + h) * 7 + pt) * HDIM + d]);
    comb[idx] = mx;
    mx = -1e30f;
#pragma unroll
    for (int pt = 0; pt < 5; pt++)
      mx = fmaxf(mx, pv1[(size_t)((n * NHEADS + h) * 5 + pt) * HDIM + d]);
    comb[300 + idx] = mx;
  }
  __syncthreads();
  float partial = 0.f;
  for (int j = tid; j < 300; j += 256) {
    float hh = b1[j];
    for (int k = 0; k < 600; k++) hh += comb[k] * w1[k * 300 + j];
    partial += fmaxf(hh, 0.f) * w2[j];
  }
  __shared__ float redd[256];
  redd[tid] = partial;
  __syncthreads();
  for (int s = 128; s > 0; s >>= 1) {
    if (tid < s) redd[tid] += redd[tid + s];
    __syncthreads();
  }
  if (tid == 0) att_score[n] = 1.0f / (1.0f + expf(-(redd[0] + b2[0])));
}

// ---------------------------------------------------------------------------
__global__ __launch_bounds__(256) void tok_kernel(
    const float* __restrict__ candg,
    const float* __restrict__ ctx2g,
    float* __restrict__ tokmax) {
  int m = blockIdx.x;
  __shared__ float cand[NN * DDIM];
  __shared__ float ctx[16 * DDIM];
  __shared__ float tokb[NN][17];
  for (int i = threadIdx.x; i < NN * DDIM; i += 256)
    cand[i] = candg[(size_t)m * NN * DDIM + i];
  int nI = threadIdx.x >> 4, tt = threadIdx.x & 15;
  for (int cbase = 0; cbase < CTX_LL; cbase += 16) {
    __syncthreads();
    for (int i = threadIdx.x; i < 16 * DDIM; i += 256) {
      int rr = i / DDIM, cc = i - rr * DDIM;
      int t = cbase + rr;
      ctx[rr * DDIM + cc] = (t < CTX_LL) ? ctx2g[(size_t)(m * CTX_LL + t) * DDIM + cc] : 0.f;
    }
    __syncthreads();
    const float4* ca = (const float4*)(cand + nI * DDIM);
    const float4* cb = (const float4*)(ctx + tt * DDIM);
    float dsum = 0.f;
#pragma unroll
    for (int c = 0; c < 75; c++) {
      float4 a = ca[c], b = cb[c];
      dsum += a.x * b.x + a.y * b.y + a.z * b.z + a.w * b.w;
    }
    tokb[nI][tt] = dsum;
    __syncthreads();
    if (threadIdx.x < 16) {
      float mx = -1e30f;
      for (int nn = 0; nn < NN; nn++) mx = fmaxf(mx, tokb[nn][threadIdx.x]);
      int t = cbase + threadIdx.x;
      if (t < CTX_LL) tokmax[m * CTX_LL + t] = mx;
    }
  }
}

// ---------------------------------------------------------------------------
__global__ __launch_bounds__(256) void ctxv_kernel(
    const float* __restrict__ tokmax,
    const float* __restrict__ ctx2g,
    const float* __restrict__ candg,
    float* __restrict__ local_att) {
  int m = blockIdx.x, tid = threadIdx.x;
  __shared__ float p[64];
  __shared__ float sctxv[DDIM];
  if (tid < 64) {
    float v = (tid < CTX_LL) ? tokmax[m * CTX_LL + tid] : -1e30f;
    float mx = v;
#pragma unroll
    for (int o = 32; o >= 1; o >>= 1) mx = fmaxf(mx, __shfl_xor(mx, o));
    float e = (tid < CTX_LL) ? expf(v - mx) : 0.f;
    float s = e;
#pragma unroll
    for (int o = 32; o >= 1; o >>= 1) s += __shfl_xor(s, o);
    p[tid] = e / s;
  }
  __syncthreads();
  for (int d = tid; d < DDIM; d += 256) {
    float acc = 0.f;
    for (int t = 0; t < CTX_LL; t++)
      acc += p[t] * ctx2g[(size_t)(m * CTX_LL + t) * DDIM + d];
    sctxv[d] = acc;
  }
  __syncthreads();
  int nI = tid >> 4, j = tid & 15;
  float dd = 0.f;
  for (int i = j; i < DDIM; i += 16)
    dd += candg[(size_t)(m * NN + nI) * DDIM + i] * sctxv[i];
#pragma unroll
  for (int o = 8; o >= 1; o >>= 1) dd += __shfl_xor(dd, o);
  if (j == 0) local_att[m * NN + nI] = dd;
}

// ---------------------------------------------------------------------------
__global__ __launch_bounds__(256) void final_kernel(
    const float* __restrict__ ms,
    const float* __restrict__ mc,       // [64][768] (already meaned)
    const float* __restrict__ title,
    const float* __restrict__ bert,
    const float* __restrict__ att_score,
    const float* __restrict__ m2c_prior,
    const float* __restrict__ hand,
    const float* __restrict__ local_att,
    const float* __restrict__ w7,
    const float* __restrict__ b7,
    float* __restrict__ out) {
  int m = blockIdx.x, tid = threadIdx.x;
  __shared__ float sms[FNUM], smc[FNUM], smd[FNUM];
  __shared__ float snorm[3], sscore[16], wred[3][4];
  for (int i = tid; i < FNUM; i += 256) {
    sms[i] = ms[m * FNUM + i];
    smc[i] = mc[m * FNUM + i];
    smd[i] = bert[i];
  }
  __syncthreads();
  float p1 = 0.f, p2 = 0.f, p3 = 0.f;
  for (int i = tid; i < FNUM; i += 256) {
    float a = sms[i], b = smc[i], c = smd[i];
    p1 += a * a; p2 += b * b; p3 += c * c;
  }
#pragma unroll
  for (int o = 32; o >= 1; o >>= 1) {
    p1 += __shfl_xor(p1, o); p2 += __shfl_xor(p2, o); p3 += __shfl_xor(p3, o);
  }
  int wid = tid >> 6, lane = tid & 63;
  if (lane == 0) { wred[0][wid] = p1; wred[1][wid] = p2; wred[2][wid] = p3; }
  __syncthreads();
  if (tid == 0) {
    snorm[0] = fmaxf(sqrtf(wred[0][0] + wred[0][1] + wred[0][2] + wred[0][3]), 1e-6f);
    snorm[1] = fmaxf(sqrtf(wred[1][0] + wred[1][1] + wred[1][2] + wred[1][3]), 1e-6f);
    snorm[2] = fmaxf(sqrtf(wred[2][0] + wred[2][1] + wred[2][2] + wred[2][3]), 1e-6f);
  }
  __syncthreads();
  int nI = tid >> 4, j = tid & 15;
  float d1 = 0.f, d2 = 0.f, d3 = 0.f, d4 = 0.f;
  for (int i = j; i < FNUM; i += 16) {
    float t = title[nI * FNUM + i];
    d1 += sms[i] * t; d2 += smc[i] * t; d3 += smd[i] * t; d4 += t * t;
  }
#pragma unroll
  for (int o = 8; o >= 1; o >>= 1) {
    d1 += __shfl_xor(d1, o); d2 += __shfl_xor(d2, o);
    d3 += __shfl_xor(d3, o); d4 += __shfl_xor(d4, o);
  }
  if (j == 0) {
    float nt = fmaxf(sqrtf(d4), 1e-6f);
    float cos_st = d1 / (snorm[0] * nt);
    float cos_ct = d2 / (snorm[1] * nt);
    float cos_dt = d3 / (snorm[2] * nt);
    float score = hand[nI] * w7[0] + m2c_prior[nI] * w7[1] +
                  local_att[m * NN + nI] * w7[2] + att_score[nI] * w7[3] +
                  cos_st * w7[4] + cos_dt * w7[5] + cos_ct * w7[6] + b7[0];
    sscore[nI] = score;
  }
  __syncthreads();
  if (tid < 16) {
    float x = sscore[tid];
    float s = x;
#pragma unroll
    for (int o = 8; o >= 1; o >>= 1) s += __shfl_xor(s, o);
    float mu = s * (1.0f / 16.0f);
    float dv = (x - mu) * (x - mu);
    float vs = dv;
#pragma unroll
    for (int o = 8; o >= 1; o >>= 1) vs += __shfl_xor(vs, o);
    float sd = sqrtf(vs * (1.0f / 15.0f));
    float z = (x - mu) / sd;
    float zm = z;
#pragma unroll
    for (int o = 8; o >= 1; o >>= 1) zm = fmaxf(zm, __shfl_xor(zm, o));
    float e = expf(z - zm);
    float es = e;
#pragma unroll
    for (int o = 8; o >= 1; o >>= 1) es += __shfl_xor(es, o);
    float sm = e / es;
    float zmin = z;
#pragma unroll
    for (int o = 8; o >= 1; o >>= 1) zmin = fminf(zmin, __shfl_xor(zmin, o));
    float u0 = (z + 1.0f - zmin) / (zm - zmin);
    float us = u0;
#pragma unroll
    for (int o = 8; o >= 1; o >>= 1) us += __shfl_xor(us, o);
    float u = u0 / us;
    out[m * NN + tid] = z;
    out[MM * NN + m * NN + tid] = sm;
    out[2 * MM * NN + m * NN + tid] = u;
  }
}

// ---------------------------------------------------------------------------
extern "C" void kernel_launch(void* const* d_in, const int* in_sizes, int n_in,
                              void* d_out, int out_size, void* d_ws, size_t ws_size,
                              hipStream_t stream) {
  const int*   mention_vec   = (const int*)d_in[3];
  const int*   context_vec   = (const int*)d_in[4];
  const int*   doc_vec       = (const int*)d_in[5];
  const float* title_vec     = (const float*)d_in[6];
  const int*   body_vec      = (const int*)d_in[7];
  const float* m2c_prior     = (const float*)d_in[9];
  const int*   men2cands     = (const int*)d_in[10];
  const int*   contexts_ids  = (const int*)d_in[11];
  const float* hand_features = (const float*)d_in[12];
  const float* bert_doc_vec  = (const float*)d_in[13];
  const float* embed_table   = (const float*)d_in[14];
  const float* conv_ms_w     = (const float*)d_in[15];
  const float* conv_ms_b     = (const float*)d_in[16];
  const float* conv_mc_w     = (const float*)d_in[17];
  const float* conv_mc_b     = (const float*)d_in[18];
  const float* layer_local_w = (const float*)d_in[19];
  const float* layer_local_b = (const float*)d_in[20];
  const float* att_w1        = (const float*)d_in[21];
  const float* att_b1        = (const float*)d_in[22];
  const float* att_w2        = (const float*)d_in[23];
  const float* att_b2        = (const float*)d_in[24];

  float* ws     = (float*)d_ws;
  float* msg    = ws + OFF_MSG;
  float* ctxg   = ws + OFF_CTXG;
  float* ctx2g  = ws + OFF_CTX2G;
  float* candg  = ws + OFF_CANDG;
  float* ms     = ws + OFF_MS;
  float* mc     = ws + OFF_MC;
  float* pv0    = ws + OFF_PV0;
  float* pv1    = ws + OFF_PV1;
  float* att_sc = ws + OFF_ASC;
  float* tokmax = ws + OFF_TOKMAX;
  float* latt   = ws + OFF_LATT;
  u16*   Abf    = (u16*)(ws + OFF_ABF);
  u16*   WTmc   = (u16*)(ws + OFF_WTMC);
  float* WTms   = ws + OFF_WTMS;
  float* Crelu  = ws + OFF_CRELU;
  float* P      = ws + OFF_P;
  float* out    = (float*)d_out;

  // gather embeddings
  gather_kernel<<<dim3(9000), dim3(256), 0, stream>>>(
      embed_table, mention_vec, context_vec, contexts_ids, men2cands, msg);
  // conv phase (uses scratch X; must finish before attn overwrites P alias)
  abuild_kernel<<<dim3(GM * GK / 2 / 256), dim3(256), 0, stream>>>(ctxg, (u32*)Abf);
  wtmc_kernel<<<dim3(GN * GK / 2 / 256), dim3(256), 0, stream>>>(conv_mc_w, (u32*)WTmc);
  wtms_kernel<<<dim3(600 * FNUM / 256), dim3(256), 0, stream>>>(conv_ms_w, WTms);
  conv_gemm_kernel<<<dim3(GM / 64, GN / 64), dim3(256), 0, stream>>>(
      Abf, WTmc, conv_mc_b, Crelu);
  conv_mean_kernel<<<dim3(MM, 3), dim3(256), 0, stream>>>(Crelu, mc);
  conv_ms_kernel<<<dim3(MM), dim3(256), 0, stream>>>(msg, WTms, conv_ms_b, ms);
  // attention phase (P aliases conv scratch; serial stream makes this safe)
  attn_scores_kernel<0><<<dim3(4, NN, NHEADS), dim3(256), 0, stream>>>(
      embed_table, doc_vec, body_vec, P);
  attn_scores_kernel<1><<<dim3(7, NN, NHEADS), dim3(256), 0, stream>>>(
      embed_table, doc_vec, body_vec, P);
  attn_pv_kernel<0><<<dim3(7, NN, NHEADS), dim3(256), 0, stream>>>(
      embed_table, doc_vec, body_vec, P, pv0);
  attn_pv_kernel<1><<<dim3(5, NN, NHEADS), dim3(256), 0, stream>>>(
      embed_table, doc_vec, body_vec, P, pv1);
  mlp_kernel<<<dim3(NN), dim3(256), 0, stream>>>(pv0, pv1, att_w1, att_b1, att_w2, att_b2, att_sc);
  // local ranker + final
  tok_kernel<<<dim3(MM), dim3(256), 0, stream>>>(candg, ctx2g, tokmax);
  ctxv_kernel<<<dim3(MM), dim3(256), 0, stream>>>(tokmax, ctx2g, candg, latt);
  final_kernel<<<dim3(MM), dim3(256), 0, stream>>>(
      ms, mc, title_vec, bert_doc_vec, att_sc, m2c_prior, hand_features,
      latt, layer_local_w, layer_local_b, out);
}

// Round 4
// 459.052 us; speedup vs baseline: 2.9240x; 1.0837x over previous
//
#include <hip/hip_runtime.h>

#define MM 64
#define NN 16
#define DDIM 300
#define FNUM 768
#define SURF_LL 4
#define CTX_LL 50
#define DOC_LL 100
#define BODY_LL 200
#define NHEADS 5
#define HDIM 60

// GEMM dims for conv_mc:  C[GM][GN] = A[GM][GK] * B^T, K padded 1500->1536
#define GM 2944   // 64 m * 46 t
#define GK 1536
#define GN 768

typedef unsigned short u16;
typedef unsigned int u32;
typedef __attribute__((ext_vector_type(8))) short short8;
typedef __attribute__((ext_vector_type(4))) float f32x4;

// ---- workspace layout (float offsets) ----
#define OFF_MSG    0                    // mention emb [256][300]
#define OFF_CTX2G  76800                // contexts_ids emb [3200][300]
#define OFF_CANDG  1036800              // men2cands emb [1024][300]
#define OFF_MS     1344000              // ms [64][768]
#define OFF_MC     1393152              // mc [64][768] (atomically accumulated mean)
#define OFF_PV0    1442304              // [16][5][2][60]
#define OFF_PV1    1451904              // [16][5][4][60]
#define OFF_ASC    1471104              // [16]
#define OFF_TOKMAX 1471120              // [64][50]
#define OFF_LATT   1474320              // [64][16]
#define OFF_ABF    1475344              // u16[GM*GK]  (16-float aligned)
#define OFF_WTMC   (OFF_ABF + GM*GK/2)  // u16[GN*GK]
#define OFF_WTMS   (OFF_WTMC + GN*GK/2) // float[600*768]
#define OFF_P      (OFF_WTMS + 600*768) // attn P [160][20000]

__device__ __forceinline__ u16 f2bf(float x) {
  union { float f; u32 u; } v; v.f = x;
  u32 r = v.u + 0x7FFFu + ((v.u >> 16) & 1u);
  return (u16)(r >> 16);
}

// ---------------------------------------------------------------------------
// Gather msg/ctx2g/candg embedding rows + zero mc (needed by gemm atomics).
// rows: [0,256) mention ; [256,3456) contexts_ids ; [3456,4480) men2cands
// grid = 5250 gather blocks + 192 zero blocks = 5442
__global__ __launch_bounds__(256) void gather_kernel(
    const float* __restrict__ embed,
    const int* __restrict__ mention_vec,
    const int* __restrict__ contexts_ids,
    const int* __restrict__ men2cands,
    float* __restrict__ dst,
    float* __restrict__ mc) {
  int e = blockIdx.x * 256 + threadIdx.x;
  if (e < 1344000) {
    int row = e / DDIM;
    int col = e - row * DDIM;
    int tok;
    if (row < 256)       tok = mention_vec[row];
    else if (row < 3456) tok = contexts_ids[row - 256];
    else                 tok = men2cands[row - 3456];
    dst[e] = embed[(size_t)tok * DDIM + col];
  } else {
    mc[e - 1344000] = 0.f;
  }
}

// ---------------------------------------------------------------------------
// Prep (merged): [0,8832) abuild im2col->bf16 (direct from embed);
// [8832,11136) conv_mc W repack n-major bf16; [11136,12936) conv_ms W^T fp32.
__global__ __launch_bounds__(256) void prep_kernel(
    const float* __restrict__ embed,
    const int* __restrict__ context_vec,   // [64][50]
    const float* __restrict__ Wmc,         // [768][300][5]
    const float* __restrict__ Wms,         // [768][300][2]
    u32* __restrict__ Abf, u32* __restrict__ WTmc, float* __restrict__ WTms) {
  int bid = blockIdx.x;
  if (bid < 8832) {
    int idx = bid * 256 + threadIdx.x;          // one u32 = 2 bf16
    int r = idx / (GK / 2);
    int kp = idx - r * (GK / 2);
    int k = kp * 2;
    int m = r / 46, t = r - m * 46;
    u32 out = 0;
#pragma unroll
    for (int j = 0; j < 2; j++) {
      int kj = k + j;
      u16 h = 0;
      if (kj < 1500) {
        int tap = kj / 300;
        int d = kj - tap * 300;
        int tok = context_vec[m * CTX_LL + t + tap];
        h = f2bf(embed[(size_t)tok * DDIM + d]);
      }
      out |= (u32)h << (16 * j);
    }
    Abf[idx] = out;
  } else if (bid < 11136) {
    int idx = (bid - 8832) * 256 + threadIdx.x;
    int n = idx / (GK / 2);
    int kp = idx - n * (GK / 2);
    int k = kp * 2;
    u32 out = 0;
#pragma unroll
    for (int j = 0; j < 2; j++) {
      int kj = k + j;
      u16 h = 0;
      if (kj < 1500) {
        int tap = kj / 300;
        int d = kj - tap * 300;
        h = f2bf(Wmc[(size_t)n * 1500 + d * 5 + tap]);
      }
      out |= (u32)h << (16 * j);
    }
    WTmc[idx] = out;
  } else {
    int idx = (bid - 11136) * 256 + threadIdx.x;  // 600*768
    int k = idx / FNUM;
    int f = idx - k * FNUM;
    WTms[idx] = Wms[(size_t)f * 600 + k];
  }
}

// ---------------------------------------------------------------------------
// bf16 MFMA GEMM with fused relu+mean epilogue (atomicAdd into mc).
// 64x64 tile, BK=64, 4 waves as 2x2, each wave 2x2 frags of 16x16x32.
__global__ __launch_bounds__(256) void conv_gemm_kernel(
    const u16* __restrict__ A,    // [GM][GK] bf16
    const u16* __restrict__ B,    // [GN][GK] bf16 (n-major)
    const float* __restrict__ bias,
    float* __restrict__ mc) {     // [64][768]
  int bn = blockIdx.x, bm = blockIdx.y;
  __shared__ u16 As[64][72];
  __shared__ u16 Bs[64][72];
  int tid = threadIdx.x;
  int w = tid >> 6, lane = tid & 63;
  int wr = w >> 1, wc = w & 1;
  int lg = lane >> 4, lm = lane & 15;
  f32x4 acc[2][2];
#pragma unroll
  for (int i = 0; i < 2; i++)
#pragma unroll
    for (int j = 0; j < 2; j++) acc[i][j] = (f32x4)0.f;
  int c0row = tid >> 3, ck = (tid & 7) * 8;
  const u16* Ag = A + (size_t)(bm * 64) * GK;
  const u16* Bg = B + (size_t)(bn * 64) * GK;
  for (int kt = 0; kt < GK / 64; kt++) {
    int k0 = kt * 64;
    uint4 av0 = *(const uint4*)(Ag + (size_t)c0row * GK + k0 + ck);
    uint4 av1 = *(const uint4*)(Ag + (size_t)(c0row + 32) * GK + k0 + ck);
    uint4 bv0 = *(const uint4*)(Bg + (size_t)c0row * GK + k0 + ck);
    uint4 bv1 = *(const uint4*)(Bg + (size_t)(c0row + 32) * GK + k0 + ck);
    __syncthreads();
    *(uint4*)&As[c0row][ck] = av0;
    *(uint4*)&As[c0row + 32][ck] = av1;
    *(uint4*)&Bs[c0row][ck] = bv0;
    *(uint4*)&Bs[c0row + 32][ck] = bv1;
    __syncthreads();
#pragma unroll
    for (int kk = 0; kk < 2; kk++) {
      short8 af0 = *(const short8*)&As[wr * 32 + lm][kk * 32 + lg * 8];
      short8 af1 = *(const short8*)&As[wr * 32 + 16 + lm][kk * 32 + lg * 8];
      short8 bf0 = *(const short8*)&Bs[wc * 32 + lm][kk * 32 + lg * 8];
      short8 bf1 = *(const short8*)&Bs[wc * 32 + 16 + lm][kk * 32 + lg * 8];
      acc[0][0] = __builtin_amdgcn_mfma_f32_16x16x32_bf16(af0, bf0, acc[0][0], 0, 0, 0);
      acc[0][1] = __builtin_amdgcn_mfma_f32_16x16x32_bf16(af0, bf1, acc[0][1], 0, 0, 0);
      acc[1][0] = __builtin_amdgcn_mfma_f32_16x16x32_bf16(af1, bf0, acc[1][0], 0, 0, 0);
      acc[1][1] = __builtin_amdgcn_mfma_f32_16x16x32_bf16(af1, bf1, acc[1][1], 0, 0, 0);
    }
  }
  // epilogue: relu, scale 1/46, reduce runs of equal m, atomicAdd into mc
#pragma unroll
  for (int mf = 0; mf < 2; mf++)
#pragma unroll
    for (int nf = 0; nf < 2; nf++) {
      int col = bn * 64 + wc * 32 + nf * 16 + lm;
      float bb = bias[col];
      int base = bm * 64 + wr * 32 + mf * 16 + lg * 4;
      int mcur = base / 46;
      float s = 0.f;
#pragma unroll
      for (int r = 0; r < 4; r++) {
        float v = fmaxf(acc[mf][nf][r] + bb, 0.f) * (1.0f / 46.0f);
        int mm = (base + r) / 46;
        if (mm != mcur) { atomicAdd(&mc[mcur * FNUM + col], s); s = 0.f; mcur = mm; }
        s += v;
      }
      atomicAdd(&mc[mcur * FNUM + col], s);
    }
}

// ---------------------------------------------------------------------------
// conv_ms: transposed weights, one filter/thread.  grid=(64,3)
__global__ __launch_bounds__(256) void conv_ms_kernel(
    const float* __restrict__ msg,   // [64][4][300]
    const float* __restrict__ WT,    // [600][768]
    const float* __restrict__ B,
    float* __restrict__ ms) {        // [64][768]
  int m = blockIdx.x;
  int f = blockIdx.y * 256 + threadIdx.x;
  const float* x = msg + m * SURF_LL * DDIM;
  float a0 = 0.f, a1 = 0.f, a2 = 0.f;
  for (int d = 0; d < DDIM; d++) {
    float v0 = x[d], v1 = x[DDIM + d], v2 = x[2 * DDIM + d], v3 = x[3 * DDIM + d];
    float wA = WT[(size_t)(2 * d) * FNUM + f];
    float wB = WT[(size_t)(2 * d + 1) * FNUM + f];
    a0 += v0 * wA + v1 * wB;
    a1 += v1 * wA + v2 * wB;
    a2 += v2 * wA + v3 * wB;
  }
  float b = B[f];
  float r = fmaxf(a0 + b, 0.f) + fmaxf(a1 + b, 0.f) + fmaxf(a2 + b, 0.f);
  ms[m * FNUM + f] = r * (1.0f / 3.0f);
}

// ---------------------------------------------------------------------------
// Fused QK^T + softmax.  Block = (q-tile of 32, n, h).
template <int DIR>
__global__ __launch_bounds__(256) void attn_scores_kernel(
    const float* __restrict__ embed,
    const int* __restrict__ doc_vec,
    const int* __restrict__ body_vec,
    float* __restrict__ P) {
  constexpr int Lq = DIR ? 200 : 100;
  constexpr int Lk = DIR ? 100 : 200;
  constexpr int KPL = DIR ? 2 : 4;
  int qt = blockIdx.x, n = blockIdx.y, h = blockIdx.z;
  const int* qids = DIR ? body_vec + n * BODY_LL : doc_vec;
  const int* kids = DIR ? doc_vec : body_vec + n * BODY_LL;
  __shared__ float Ks[Lk * 61];
  __shared__ float Qs[32 * 61];
  for (int idx = threadIdx.x; idx < Lk * 15; idx += 256) {
    int r = idx / 15, c = idx - r * 15;
    float4 v = *(const float4*)(embed + (size_t)kids[r] * DDIM + h * HDIM + c * 4);
    float* dp = Ks + r * 61 + c * 4;
    dp[0] = v.x; dp[1] = v.y; dp[2] = v.z; dp[3] = v.w;
  }
  for (int idx = threadIdx.x; idx < 32 * 15; idx += 256) {
    int r = idx / 15, c = idx - r * 15;
    int q = qt * 32 + r; if (q >= Lq) q = Lq - 1;
    float4 v = *(const float4*)(embed + (size_t)qids[q] * DDIM + h * HDIM + c * 4);
    float* dp = Qs + r * 61 + c * 4;
    dp[0] = v.x; dp[1] = v.y; dp[2] = v.z; dp[3] = v.w;
  }
  __syncthreads();
  int w = threadIdx.x >> 6, lane = threadIdx.x & 63;
  float acc[8][KPL];
#pragma unroll
  for (int i = 0; i < 8; i++)
#pragma unroll
    for (int j = 0; j < KPL; j++) acc[i][j] = 0.f;
  for (int d = 0; d < HDIM; d++) {
    float kv[KPL];
#pragma unroll
    for (int j = 0; j < KPL; j++) {
      int kk = lane + 64 * j; if (kk >= Lk) kk = Lk - 1;
      kv[j] = Ks[kk * 61 + d];
    }
#pragma unroll
    for (int i = 0; i < 8; i++) {
      float qv = Qs[(w * 8 + i) * 61 + d];
#pragma unroll
      for (int j = 0; j < KPL; j++) acc[i][j] += qv * kv[j];
    }
  }
  const float scale = 0.12909944487358056f;  // 1/sqrt(60)
#pragma unroll
  for (int i = 0; i < 8; i++) {
    int q = qt * 32 + w * 8 + i;
    float mx = -1e30f;
#pragma unroll
    for (int j = 0; j < KPL; j++)
      if (lane + 64 * j < Lk) mx = fmaxf(mx, acc[i][j]);
#pragma unroll
    for (int o = 32; o >= 1; o >>= 1) mx = fmaxf(mx, __shfl_xor(mx, o));
    float mxs = mx * scale;
    float p[KPL];
    float s = 0.f;
#pragma unroll
    for (int j = 0; j < KPL; j++) {
      p[j] = (lane + 64 * j < Lk) ? __expf(acc[i][j] * scale - mxs) : 0.f;
      s += p[j];
    }
#pragma unroll
    for (int o = 32; o >= 1; o >>= 1) s += __shfl_xor(s, o);
    float inv = 1.0f / s;
    if (q < Lq) {
      float* rowp = P + (size_t)((n * 2 + DIR) * NHEADS + h) * 20000 + q * Lk;
#pragma unroll
      for (int j = 0; j < KPL; j++) {
        int kk = lane + 64 * j;
        if (kk < Lk) rowp[kk] = p[j] * inv;
      }
    }
  }
}

// ---------------------------------------------------------------------------
// PV + max-pool over q, both dirs merged.  Block covers 64 q (4 waves x 4 q x
// 4 passes).  K transposed in LDS: Kt4[d][k4] float4, row stride 51/27 float4
// (stride mod 32 == 12 -> bank-quad balanced b128).  P rows are wave-uniform
// float4 global loads (scalar path; P is L2-hot).
// grid: dir0 2*80=160 blocks, dir1 4*80=320 -> 480 linear.
__global__ __launch_bounds__(256) void attn_pv_kernel(
    const float* __restrict__ embed,
    const int* __restrict__ doc_vec,
    const int* __restrict__ body_vec,
    const float* __restrict__ P,
    float* __restrict__ pv0,   // [16][5][2][60]
    float* __restrict__ pv1) { // [16][5][4][60]
  int bid = blockIdx.x;
  int dir, pt, n, h;
  if (bid < 160) { dir = 0; h = bid % 5; n = (bid / 5) % 16; pt = bid / 80; }
  else { int b = bid - 160; dir = 1; h = b % 5; n = (b / 5) % 16; pt = b / 80; }
  int Lq = dir ? 200 : 100;
  int Lk = dir ? 100 : 200;
  int Lk4 = Lk >> 2;
  int K4STR = dir ? 27 : 51;  // float4 row stride; *4 dwords mod 32 == 12
  const int* kids = dir ? doc_vec : body_vec + n * BODY_LL;
  __shared__ float4 Kt4[60 * 51];
  __shared__ float red[4][64];
  float* Ktf = (float*)Kt4;
  int RS = K4STR * 4;  // row stride in floats
  for (int idx = threadIdx.x; idx < Lk * 15; idx += 256) {
    int r = idx / 15, c = idx - r * 15;  // k row, d-chunk
    float4 v = *(const float4*)(embed + (size_t)kids[r] * DDIM + h * HDIM + c * 4);
    Ktf[(c * 4 + 0) * RS + r] = v.x;
    Ktf[(c * 4 + 1) * RS + r] = v.y;
    Ktf[(c * 4 + 2) * RS + r] = v.z;
    Ktf[(c * 4 + 3) * RS + r] = v.w;
  }
  __syncthreads();
  int lane = threadIdx.x & 63;
  int w = __builtin_amdgcn_readfirstlane(threadIdx.x >> 6);
  int dl = (lane < HDIM) ? lane : (HDIM - 1);
  const float4* Krow = Kt4 + dl * K4STR;
  const float* Pb = P + (size_t)((n * 2 + dir) * NHEADS + h) * 20000;
  float omax = -1e30f;
#pragma unroll
  for (int p = 0; p < 4; p++) {
    int q0 = pt * 64 + p * 16 + w * 4;
    int qa0 = min(q0, Lq - 1), qa1 = min(q0 + 1, Lq - 1);
    int qa2 = min(q0 + 2, Lq - 1), qa3 = min(q0 + 3, Lq - 1);
    const float4* P0 = (const float4*)(Pb + (size_t)qa0 * Lk);
    const float4* P1 = (const float4*)(Pb + (size_t)qa1 * Lk);
    const float4* P2 = (const float4*)(Pb + (size_t)qa2 * Lk);
    const float4* P3 = (const float4*)(Pb + (size_t)qa3 * Lk);
    float o0 = 0.f, o1 = 0.f, o2 = 0.f, o3 = 0.f;
    for (int k4 = 0; k4 < Lk4; k4++) {
      float4 pp0 = P0[k4], pp1 = P1[k4], pp2 = P2[k4], pp3 = P3[k4];
      float4 kk = Krow[k4];
      o0 += pp0.x * kk.x + pp0.y * kk.y + pp0.z * kk.z + pp0.w * kk.w;
      o1 += pp1.x * kk.x + pp1.y * kk.y + pp1.z * kk.z + pp1.w * kk.w;
      o2 += pp2.x * kk.x + pp2.y * kk.y + pp2.z * kk.z + pp2.w * kk.w;
      o3 += pp3.x * kk.x + pp3.y * kk.y + pp3.z * kk.z + pp3.w * kk.w;
    }
    if (q0 < Lq)     omax = fmaxf(omax, o0);
    if (q0 + 1 < Lq) omax = fmaxf(omax, o1);
    if (q0 + 2 < Lq) omax = fmaxf(omax, o2);
    if (q0 + 3 < Lq) omax = fmaxf(omax, o3);
  }
  red[threadIdx.x >> 6][lane] = omax;
  __syncthreads();
  if (threadIdx.x < 64 && lane < HDIM) {
    float m4 = fmaxf(fmaxf(red[0][lane], red[1][lane]),
                     fmaxf(red[2][lane], red[3][lane]));
    float* dst = dir ? pv1 + (size_t)((n * NHEADS + h) * 4 + pt) * HDIM
                     : pv0 + (size_t)((n * NHEADS + h) * 2 + pt) * HDIM;
    dst[lane] = m4;
  }
}

// ---------------------------------------------------------------------------
// Combine pv partials (max over tiles) then MLP + sigmoid.  grid=16
__global__ __launch_bounds__(256) void mlp_kernel(
    const float* __restrict__ pv0, const float* __restrict__ pv1,
    const float* __restrict__ w1, const float* __restrict__ b1,
    const float* __restrict__ w2, const float* __restrict__ b2,
    float* __restrict__ att_score) {
  int n = blockIdx.x, tid = threadIdx.x;
  __shared__ float comb[600];
  for (int idx = tid; idx < 300; idx += 256) {
    int h = idx / 60, d = idx - h * 60;
    float mx = -1e30f;
#pragma unroll
    for (int pt = 0; pt < 2; pt++)
      mx = fmaxf(mx, pv0[(size_t)((n * NHEADS + h) * 2 + pt) * HDIM + d]);
    comb[idx] = mx;
    mx = -1e30f;
#pragma unroll
    for (int pt = 0; pt < 4; pt++)
      mx = fmaxf(mx, pv1[(size_t)((n * NHEADS + h) * 4 + pt) * HDIM + d]);
    comb[300 + idx] = mx;
  }
  __syncthreads();
  float partial = 0.f;
  for (int j = tid; j < 300; j += 256) {
    float hh = b1[j];
    for (int k = 0; k < 600; k++) hh += comb[k] * w1[k * 300 + j];
    partial += fmaxf(hh, 0.f) * w2[j];
  }
  __shared__ float redd[256];
  redd[tid] = partial;
  __syncthreads();
  for (int s = 128; s > 0; s >>= 1) {
    if (tid < s) redd[tid] += redd[tid + s];
    __syncthreads();
  }
  if (tid == 0) att_score[n] = 1.0f / (1.0f + expf(-(redd[0] + b2[0])));
}

// ---------------------------------------------------------------------------
// tok + max over candidates.  grid=(64,2): y covers 2 ctx tiles each.
__global__ __launch_bounds__(256) void tok_kernel(
    const float* __restrict__ candg,
    const float* __restrict__ ctx2g,
    float* __restrict__ tokmax) {
  int m = blockIdx.x;
  __shared__ float cand[NN * DDIM];
  __shared__ float ctx[16 * DDIM];
  __shared__ float tokb[NN][17];
  for (int i = threadIdx.x; i < NN * DDIM; i += 256)
    cand[i] = candg[(size_t)m * NN * DDIM + i];
  int nI = threadIdx.x >> 4, tt = threadIdx.x & 15;
  for (int cb2 = 0; cb2 < 2; cb2++) {
    int cbase = blockIdx.y * 32 + cb2 * 16;
    __syncthreads();
    for (int i = threadIdx.x; i < 16 * DDIM; i += 256) {
      int rr = i / DDIM, cc = i - rr * DDIM;
      int t = cbase + rr;
      ctx[rr * DDIM + cc] = (t < CTX_LL) ? ctx2g[(size_t)(m * CTX_LL + t) * DDIM + cc] : 0.f;
    }
    __syncthreads();
    const float4* ca = (const float4*)(cand + nI * DDIM);
    const float4* cb = (const float4*)(ctx + tt * DDIM);
    float dsum = 0.f;
#pragma unroll
    for (int c = 0; c < 75; c++) {
      float4 a = ca[c], b = cb[c];
      dsum += a.x * b.x + a.y * b.y + a.z * b.z + a.w * b.w;
    }
    tokb[nI][tt] = dsum;
    __syncthreads();
    if (threadIdx.x < 16) {
      float mx = -1e30f;
      for (int nn = 0; nn < NN; nn++) mx = fmaxf(mx, tokb[nn][threadIdx.x]);
      int t = cbase + threadIdx.x;
      if (t < CTX_LL) tokmax[m * CTX_LL + t] = mx;
    }
  }
}

// ---------------------------------------------------------------------------
__global__ __launch_bounds__(256) void ctxv_kernel(
    const float* __restrict__ tokmax,
    const float* __restrict__ ctx2g,
    const float* __restrict__ candg,
    float* __restrict__ local_att) {
  int m = blockIdx.x, tid = threadIdx.x;
  __shared__ float p[64];
  __shared__ float sctxv[DDIM];
  if (tid < 64) {
    float v = (tid < CTX_LL) ? tokmax[m * CTX_LL + tid] : -1e30f;
    float mx = v;
#pragma unroll
    for (int o = 32; o >= 1; o >>= 1) mx = fmaxf(mx, __shfl_xor(mx, o));
    float e = (tid < CTX_LL) ? expf(v - mx) : 0.f;
    float s = e;
#pragma unroll
    for (int o = 32; o >= 1; o >>= 1) s += __shfl_xor(s, o);
    p[tid] = e / s;
  }
  __syncthreads();
  for (int d = tid; d < DDIM; d += 256) {
    float acc = 0.f;
    for (int t = 0; t < CTX_LL; t++)
      acc += p[t] * ctx2g[(size_t)(m * CTX_LL + t) * DDIM + d];
    sctxv[d] = acc;
  }
  __syncthreads();
  int nI = tid >> 4, j = tid & 15;
  float dd = 0.f;
  for (int i = j; i < DDIM; i += 16)
    dd += candg[(size_t)(m * NN + nI) * DDIM + i] * sctxv[i];
#pragma unroll
  for (int o = 8; o >= 1; o >>= 1) dd += __shfl_xor(dd, o);
  if (j == 0) local_att[m * NN + nI] = dd;
}

// ---------------------------------------------------------------------------
__global__ __launch_bounds__(256) void final_kernel(
    const float* __restrict__ ms,
    const float* __restrict__ mc,
    const float* __restrict__ title,
    const float* __restrict__ bert,
    const float* __restrict__ att_score,
    const float* __restrict__ m2c_prior,
    const float* __restrict__ hand,
    const float* __restrict__ local_att,
    const float* __restrict__ w7,
    const float* __restrict__ b7,
    float* __restrict__ out) {
  int m = blockIdx.x, tid = threadIdx.x;
  __shared__ float sms[FNUM], smc[FNUM], smd[FNUM];
  __shared__ float snorm[3], sscore[16], wred[3][4];
  for (int i = tid; i < FNUM; i += 256) {
    sms[i] = ms[m * FNUM + i];
    smc[i] = mc[m * FNUM + i];
    smd[i] = bert[i];
  }
  __syncthreads();
  float p1 = 0.f, p2 = 0.f, p3 = 0.f;
  for (int i = tid; i < FNUM; i += 256) {
    float a = sms[i], b = smc[i], c = smd[i];
    p1 += a * a; p2 += b * b; p3 += c * c;
  }
#pragma unroll
  for (int o = 32; o >= 1; o >>= 1) {
    p1 += __shfl_xor(p1, o); p2 += __shfl_xor(p2, o); p3 += __shfl_xor(p3, o);
  }
  int wid = tid >> 6, lane = tid & 63;
  if (lane == 0) { wred[0][wid] = p1; wred[1][wid] = p2; wred[2][wid] = p3; }
  __syncthreads();
  if (tid == 0) {
    snorm[0] = fmaxf(sqrtf(wred[0][0] + wred[0][1] + wred[0][2] + wred[0][3]), 1e-6f);
    snorm[1] = fmaxf(sqrtf(wred[1][0] + wred[1][1] + wred[1][2] + wred[1][3]), 1e-6f);
    snorm[2] = fmaxf(sqrtf(wred[2][0] + wred[2][1] + wred[2][2] + wred[2][3]), 1e-6f);
  }
  __syncthreads();
  int nI = tid >> 4, j = tid & 15;
  float d1 = 0.f, d2 = 0.f, d3 = 0.f, d4 = 0.f;
  for (int i = j; i < FNUM; i += 16) {
    float t = title[nI * FNUM + i];
    d1 += sms[i] * t; d2 += smc[i] * t; d3 += smd[i] * t; d4 += t * t;
  }
#pragma unroll
  for (int o = 8; o >= 1; o >>= 1) {
    d1 += __shfl_xor(d1, o); d2 += __shfl_xor(d2, o);
    d3 += __shfl_xor(d3, o); d4 += __shfl_xor(d4, o);
  }
  if (j == 0) {
    float nt = fmaxf(sqrtf(d4), 1e-6f);
    float cos_st = d1 / (snorm[0] * nt);
    float cos_ct = d2 / (snorm[1] * nt);
    float cos_dt = d3 / (snorm[2] * nt);
    float score = hand[nI] * w7[0] + m2c_prior[nI] * w7[1] +
                  local_att[m * NN + nI] * w7[2] + att_score[nI] * w7[3] +
                  cos_st * w7[4] + cos_dt * w7[5] + cos_ct * w7[6] + b7[0];
    sscore[nI] = score;
  }
  __syncthreads();
  if (tid < 16) {
    float x = sscore[tid];
    float s = x;
#pragma unroll
    for (int o = 8; o >= 1; o >>= 1) s += __shfl_xor(s, o);
    float mu = s * (1.0f / 16.0f);
    float dv = (x - mu) * (x - mu);
    float vs = dv;
#pragma unroll
    for (int o = 8; o >= 1; o >>= 1) vs += __shfl_xor(vs, o);
    float sd = sqrtf(vs * (1.0f / 15.0f));
    float z = (x - mu) / sd;
    float zm = z;
#pragma unroll
    for (int o = 8; o >= 1; o >>= 1) zm = fmaxf(zm, __shfl_xor(zm, o));
    float e = expf(z - zm);
    float es = e;
#pragma unroll
    for (int o = 8; o >= 1; o >>= 1) es += __shfl_xor(es, o);
    float sm = e / es;
    float zmin = z;
#pragma unroll
    for (int o = 8; o >= 1; o >>= 1) zmin = fminf(zmin, __shfl_xor(zmin, o));
    float u0 = (z + 1.0f - zmin) / (zm - zmin);
    float us = u0;
#pragma unroll
    for (int o = 8; o >= 1; o >>= 1) us += __shfl_xor(us, o);
    float u = u0 / us;
    out[m * NN + tid] = z;
    out[MM * NN + m * NN + tid] = sm;
    out[2 * MM * NN + m * NN + tid] = u;
  }
}

// ---------------------------------------------------------------------------
extern "C" void kernel_launch(void* const* d_in, const int* in_sizes, int n_in,
                              void* d_out, int out_size, void* d_ws, size_t ws_size,
                              hipStream_t stream) {
  const int*   mention_vec   = (const int*)d_in[3];
  const int*   context_vec   = (const int*)d_in[4];
  const int*   doc_vec       = (const int*)d_in[5];
  const float* title_vec     = (const float*)d_in[6];
  const int*   body_vec      = (const int*)d_in[7];
  const float* m2c_prior     = (const float*)d_in[9];
  const int*   men2cands     = (const int*)d_in[10];
  const int*   contexts_ids  = (const int*)d_in[11];
  const float* hand_features = (const float*)d_in[12];
  const float* bert_doc_vec  = (const float*)d_in[13];
  const float* embed_table   = (const float*)d_in[14];
  const float* conv_ms_w     = (const float*)d_in[15];
  const float* conv_ms_b     = (const float*)d_in[16];
  const float* conv_mc_w     = (const float*)d_in[17];
  const float* conv_mc_b     = (const float*)d_in[18];
  const float* layer_local_w = (const float*)d_in[19];
  const float* layer_local_b = (const float*)d_in[20];
  const float* att_w1        = (const float*)d_in[21];
  const float* att_b1        = (const float*)d_in[22];
  const float* att_w2        = (const float*)d_in[23];
  const float* att_b2        = (const float*)d_in[24];

  float* ws     = (float*)d_ws;
  float* msg    = ws + OFF_MSG;
  float* ctx2g  = ws + OFF_CTX2G;
  float* candg  = ws + OFF_CANDG;
  float* ms     = ws + OFF_MS;
  float* mc     = ws + OFF_MC;
  float* pv0    = ws + OFF_PV0;
  float* pv1    = ws + OFF_PV1;
  float* att_sc = ws + OFF_ASC;
  float* tokmax = ws + OFF_TOKMAX;
  float* latt   = ws + OFF_LATT;
  u16*   Abf    = (u16*)(ws + OFF_ABF);
  u16*   WTmc   = (u16*)(ws + OFF_WTMC);
  float* WTms   = ws + OFF_WTMS;
  float* P      = ws + OFF_P;
  float* out    = (float*)d_out;

  gather_kernel<<<dim3(5442), dim3(256), 0, stream>>>(
      embed_table, mention_vec, contexts_ids, men2cands, ws, mc);
  prep_kernel<<<dim3(12936), dim3(256), 0, stream>>>(
      embed_table, context_vec, conv_mc_w, conv_ms_w, (u32*)Abf, (u32*)WTmc, WTms);
  conv_gemm_kernel<<<dim3(GN / 64, GM / 64), dim3(256), 0, stream>>>(
      Abf, WTmc, conv_mc_b, mc);
  conv_ms_kernel<<<dim3(MM, 3), dim3(256), 0, stream>>>(msg, WTms, conv_ms_b, ms);
  attn_scores_kernel<0><<<dim3(4, NN, NHEADS), dim3(256), 0, stream>>>(
      embed_table, doc_vec, body_vec, P);
  attn_scores_kernel<1><<<dim3(7, NN, NHEADS), dim3(256), 0, stream>>>(
      embed_table, doc_vec, body_vec, P);
  attn_pv_kernel<<<dim3(480), dim3(256), 0, stream>>>(
      embed_table, doc_vec, body_vec, P, pv0, pv1);
  mlp_kernel<<<dim3(NN), dim3(256), 0, stream>>>(pv0, pv1, att_w1, att_b1, att_w2, att_b2, att_sc);
  tok_kernel<<<dim3(MM, 2), dim3(256), 0, stream>>>(candg, ctx2g, tokmax);
  ctxv_kernel<<<dim3(MM), dim3(256), 0, stream>>>(tokmax, ctx2g, candg, latt);
  final_kernel<<<dim3(MM), dim3(256), 0, stream>>>(
      ms, mc, title_vec, bert_doc_vec, att_sc, m2c_prior, hand_features,
      latt, layer_local_w, layer_local_b, out);
}

// Round 5
// 418.942 us; speedup vs baseline: 3.2040x; 1.0957x over previous
//
#include <hip/hip_runtime.h>

#define MM 64
#define NN 16
#define DDIM 300
#define FNUM 768
#define SURF_LL 4
#define CTX_LL 50
#define DOC_LL 100
#define BODY_LL 200
#define NHEADS 5
#define HDIM 60

// GEMM dims for conv_mc:  C[GM][GN] = A[GM][GK] * B^T, K padded 1500->1536
#define GM 2944   // 64 m * 46 t
#define GK 1536
#define GN 768

typedef unsigned short u16;
typedef unsigned int u32;
typedef __attribute__((ext_vector_type(8))) short short8;
typedef __attribute__((ext_vector_type(4))) float f32x4;

// ---- workspace layout (float offsets) ----
#define OFF_MSG    0                    // mention emb [256][300]
#define OFF_CTX2G  76800                // contexts_ids emb [3200][300]
#define OFF_CANDG  1036800              // men2cands emb [1024][300]
#define OFF_MS     1344000              // ms [64][768]
#define OFF_MC     1393152              // mc [64][768] (atomic mean accum)
#define OFF_PV0    1442304              // [16][5][2][60]
#define OFF_PV1    1451904              // [16][5][4][60]
#define OFF_ASC    1471104              // [16]
#define OFF_LATT   1471120              // [64][16]
#define OFF_ABF    1472144              // u16[GM*GK]
#define OFF_WTMC   (OFF_ABF + GM*GK/2)  // u16[GN*GK]
#define OFF_WTMS   (OFF_WTMC + GN*GK/2) // float[600*768]
#define OFF_P      (OFF_WTMS + 600*768) // attn P [160][20000]

__device__ __forceinline__ u16 f2bf(float x) {
  union { float f; u32 u; } v; v.f = x;
  u32 r = v.u + 0x7FFFu + ((v.u >> 16) & 1u);
  return (u16)(r >> 16);
}

// ---------------------------------------------------------------------------
// MEGA-PREP: gather embeddings + zero mc + im2col bf16 + weight repacks.
// blocks: [0,5250) gather ; [5250,5442) mc zero ; [5442,14274) abuild ;
//         [14274,16578) wtmc ; [16578,18378) wtms
__global__ __launch_bounds__(256) void mega_prep_kernel(
    const float* __restrict__ embed,
    const int* __restrict__ mention_vec,
    const int* __restrict__ context_vec,
    const int* __restrict__ contexts_ids,
    const int* __restrict__ men2cands,
    const float* __restrict__ Wmc,
    const float* __restrict__ Wms,
    float* __restrict__ dst, float* __restrict__ mc,
    u32* __restrict__ Abf, u32* __restrict__ WTmc, float* __restrict__ WTms) {
  int bid = blockIdx.x;
  if (bid < 5250) {
    int e = bid * 256 + threadIdx.x;
    int row = e / DDIM;
    int col = e - row * DDIM;
    int tok;
    if (row < 256)       tok = mention_vec[row];
    else if (row < 3456) tok = contexts_ids[row - 256];
    else                 tok = men2cands[row - 3456];
    dst[e] = embed[(size_t)tok * DDIM + col];
  } else if (bid < 5442) {
    mc[(bid - 5250) * 256 + threadIdx.x] = 0.f;
  } else if (bid < 14274) {
    int idx = (bid - 5442) * 256 + threadIdx.x;  // one u32 = 2 bf16
    int r = idx / (GK / 2);
    int kp = idx - r * (GK / 2);
    int k = kp * 2;
    int m = r / 46, t = r - m * 46;
    u32 out = 0;
#pragma unroll
    for (int j = 0; j < 2; j++) {
      int kj = k + j;
      u16 h = 0;
      if (kj < 1500) {
        int tap = kj / 300;
        int d = kj - tap * 300;
        int tok = context_vec[m * CTX_LL + t + tap];
        h = f2bf(embed[(size_t)tok * DDIM + d]);
      }
      out |= (u32)h << (16 * j);
    }
    Abf[idx] = out;
  } else if (bid < 16578) {
    int idx = (bid - 14274) * 256 + threadIdx.x;
    int n = idx / (GK / 2);
    int kp = idx - n * (GK / 2);
    int k = kp * 2;
    u32 out = 0;
#pragma unroll
    for (int j = 0; j < 2; j++) {
      int kj = k + j;
      u16 h = 0;
      if (kj < 1500) {
        int tap = kj / 300;
        int d = kj - tap * 300;
        h = f2bf(Wmc[(size_t)n * 1500 + d * 5 + tap]);
      }
      out |= (u32)h << (16 * j);
    }
    WTmc[idx] = out;
  } else {
    int idx = (bid - 16578) * 256 + threadIdx.x;  // 600*768
    int k = idx / FNUM;
    int f = idx - k * FNUM;
    WTms[idx] = Wms[(size_t)f * 600 + k];
  }
}

// ---------------------------------------------------------------------------
// bf16 MFMA GEMM with fused relu+mean epilogue (atomicAdd into mc).
__global__ __launch_bounds__(256) void conv_gemm_kernel(
    const u16* __restrict__ A,    // [GM][GK] bf16
    const u16* __restrict__ B,    // [GN][GK] bf16 (n-major)
    const float* __restrict__ bias,
    float* __restrict__ mc) {     // [64][768]
  int bn = blockIdx.x, bm = blockIdx.y;
  __shared__ u16 As[64][72];
  __shared__ u16 Bs[64][72];
  int tid = threadIdx.x;
  int w = tid >> 6, lane = tid & 63;
  int wr = w >> 1, wc = w & 1;
  int lg = lane >> 4, lm = lane & 15;
  f32x4 acc[2][2];
#pragma unroll
  for (int i = 0; i < 2; i++)
#pragma unroll
    for (int j = 0; j < 2; j++) acc[i][j] = (f32x4)0.f;
  int c0row = tid >> 3, ck = (tid & 7) * 8;
  const u16* Ag = A + (size_t)(bm * 64) * GK;
  const u16* Bg = B + (size_t)(bn * 64) * GK;
  for (int kt = 0; kt < GK / 64; kt++) {
    int k0 = kt * 64;
    uint4 av0 = *(const uint4*)(Ag + (size_t)c0row * GK + k0 + ck);
    uint4 av1 = *(const uint4*)(Ag + (size_t)(c0row + 32) * GK + k0 + ck);
    uint4 bv0 = *(const uint4*)(Bg + (size_t)c0row * GK + k0 + ck);
    uint4 bv1 = *(const uint4*)(Bg + (size_t)(c0row + 32) * GK + k0 + ck);
    __syncthreads();
    *(uint4*)&As[c0row][ck] = av0;
    *(uint4*)&As[c0row + 32][ck] = av1;
    *(uint4*)&Bs[c0row][ck] = bv0;
    *(uint4*)&Bs[c0row + 32][ck] = bv1;
    __syncthreads();
#pragma unroll
    for (int kk = 0; kk < 2; kk++) {
      short8 af0 = *(const short8*)&As[wr * 32 + lm][kk * 32 + lg * 8];
      short8 af1 = *(const short8*)&As[wr * 32 + 16 + lm][kk * 32 + lg * 8];
      short8 bf0 = *(const short8*)&Bs[wc * 32 + lm][kk * 32 + lg * 8];
      short8 bf1 = *(const short8*)&Bs[wc * 32 + 16 + lm][kk * 32 + lg * 8];
      acc[0][0] = __builtin_amdgcn_mfma_f32_16x16x32_bf16(af0, bf0, acc[0][0], 0, 0, 0);
      acc[0][1] = __builtin_amdgcn_mfma_f32_16x16x32_bf16(af0, bf1, acc[0][1], 0, 0, 0);
      acc[1][0] = __builtin_amdgcn_mfma_f32_16x16x32_bf16(af1, bf0, acc[1][0], 0, 0, 0);
      acc[1][1] = __builtin_amdgcn_mfma_f32_16x16x32_bf16(af1, bf1, acc[1][1], 0, 0, 0);
    }
  }
#pragma unroll
  for (int mf = 0; mf < 2; mf++)
#pragma unroll
    for (int nf = 0; nf < 2; nf++) {
      int col = bn * 64 + wc * 32 + nf * 16 + lm;
      float bb = bias[col];
      int base = bm * 64 + wr * 32 + mf * 16 + lg * 4;
      int mcur = base / 46;
      float s = 0.f;
#pragma unroll
      for (int r = 0; r < 4; r++) {
        float v = fmaxf(acc[mf][nf][r] + bb, 0.f) * (1.0f / 46.0f);
        int mm = (base + r) / 46;
        if (mm != mcur) { atomicAdd(&mc[mcur * FNUM + col], s); s = 0.f; mcur = mm; }
        s += v;
      }
      atomicAdd(&mc[mcur * FNUM + col], s);
    }
}

// ---------------------------------------------------------------------------
// device bodies for the MEGA-MID kernel
__device__ __forceinline__ void conv_ms_body(
    const float* __restrict__ msg, const float* __restrict__ WT,
    const float* __restrict__ B, float* __restrict__ ms, int b) {
  int m = b / 3, fi = b - m * 3;
  int f = fi * 256 + threadIdx.x;
  const float* x = msg + m * SURF_LL * DDIM;
  float a0 = 0.f, a1 = 0.f, a2 = 0.f;
  for (int d = 0; d < DDIM; d++) {
    float v0 = x[d], v1 = x[DDIM + d], v2 = x[2 * DDIM + d], v3 = x[3 * DDIM + d];
    float wA = WT[(size_t)(2 * d) * FNUM + f];
    float wB = WT[(size_t)(2 * d + 1) * FNUM + f];
    a0 += v0 * wA + v1 * wB;
    a1 += v1 * wA + v2 * wB;
    a2 += v2 * wA + v3 * wB;
  }
  float bb = B[f];
  float r = fmaxf(a0 + bb, 0.f) + fmaxf(a1 + bb, 0.f) + fmaxf(a2 + bb, 0.f);
  ms[m * FNUM + f] = r * (1.0f / 3.0f);
}

// Fused QK^T + softmax.  K rows stride 62 (b64, 2-way bank = free); Q rows
// stride 64 (b128 broadcast).  Wave w computes 8 q rows x KPL k-cols/lane.
template <int DIR>
__device__ __forceinline__ void scores_body(
    const float* __restrict__ embed, const int* __restrict__ doc_vec,
    const int* __restrict__ body_vec, float* __restrict__ P, int b,
    float* __restrict__ smem) {
  constexpr int Lq = DIR ? 200 : 100;
  constexpr int Lk = DIR ? 100 : 200;
  constexpr int KPL = DIR ? 2 : 4;
  int qt = b / 80;
  int rem = b - qt * 80;
  int n = rem / 5, h = rem - n * 5;
  const int* qids = DIR ? body_vec + n * BODY_LL : doc_vec;
  const int* kids = DIR ? doc_vec : body_vec + n * BODY_LL;
  float* Ks = smem;             // [Lk][62]
  float* Qs = smem + Lk * 62;   // [32][64]
  for (int idx = threadIdx.x; idx < Lk * 15; idx += 256) {
    int r = idx / 15, c = idx - r * 15;
    float4 v = *(const float4*)(embed + (size_t)kids[r] * DDIM + h * HDIM + c * 4);
    float* dp = Ks + r * 62 + c * 4;
    dp[0] = v.x; dp[1] = v.y; dp[2] = v.z; dp[3] = v.w;
  }
  for (int idx = threadIdx.x; idx < 32 * 15; idx += 256) {
    int r = idx / 15, c = idx - r * 15;
    int q = qt * 32 + r; if (q >= Lq) q = Lq - 1;
    float4 v = *(const float4*)(embed + (size_t)qids[q] * DDIM + h * HDIM + c * 4);
    float* dp = Qs + r * 64 + c * 4;
    dp[0] = v.x; dp[1] = v.y; dp[2] = v.z; dp[3] = v.w;
  }
  __syncthreads();
  int w = threadIdx.x >> 6, lane = threadIdx.x & 63;
  int kcl[KPL];
#pragma unroll
  for (int j = 0; j < KPL; j++) {
    int kk = lane + 64 * j; kcl[j] = (kk < Lk) ? kk : (Lk - 1);
  }
  float acc[8][KPL];
#pragma unroll
  for (int i = 0; i < 8; i++)
#pragma unroll
    for (int j = 0; j < KPL; j++) acc[i][j] = 0.f;
  for (int d = 0; d < HDIM; d += 4) {
    float2 kva[KPL], kvb[KPL];
#pragma unroll
    for (int j = 0; j < KPL; j++) {
      kva[j] = *(const float2*)&Ks[kcl[j] * 62 + d];
      kvb[j] = *(const float2*)&Ks[kcl[j] * 62 + d + 2];
    }
#pragma unroll
    for (int i = 0; i < 8; i++) {
      float4 qv = *(const float4*)&Qs[(w * 8 + i) * 64 + d];
#pragma unroll
      for (int j = 0; j < KPL; j++)
        acc[i][j] += qv.x * kva[j].x + qv.y * kva[j].y +
                     qv.z * kvb[j].x + qv.w * kvb[j].y;
    }
  }
  const float scale = 0.12909944487358056f;  // 1/sqrt(60)
#pragma unroll
  for (int i = 0; i < 8; i++) {
    int q = qt * 32 + w * 8 + i;
    float mx = -1e30f;
#pragma unroll
    for (int j = 0; j < KPL; j++)
      if (lane + 64 * j < Lk) mx = fmaxf(mx, acc[i][j]);
#pragma unroll
    for (int o = 32; o >= 1; o >>= 1) mx = fmaxf(mx, __shfl_xor(mx, o));
    float mxs = mx * scale;
    float p[KPL];
    float s = 0.f;
#pragma unroll
    for (int j = 0; j < KPL; j++) {
      p[j] = (lane + 64 * j < Lk) ? __expf(acc[i][j] * scale - mxs) : 0.f;
      s += p[j];
    }
#pragma unroll
    for (int o = 32; o >= 1; o >>= 1) s += __shfl_xor(s, o);
    float inv = 1.0f / s;
    if (q < Lq) {
      float* rowp = P + (size_t)((n * 2 + DIR) * NHEADS + h) * 20000 + q * Lk;
#pragma unroll
      for (int j = 0; j < KPL; j++) {
        int kk = lane + 64 * j;
        if (kk < Lk) rowp[kk] = p[j] * inv;
      }
    }
  }
}

// tok + ctxv fused, one block per m; tokmax/p stay in LDS; cand reused for
// the final dot from LDS.
__device__ __forceinline__ void tokctxv_body(
    const float* __restrict__ candg, const float* __restrict__ ctx2g,
    float* __restrict__ local_att, int m, float* __restrict__ smem) {
  float* cand  = smem;          // [16][300]
  float* ctx   = smem + 4800;   // [16][300]
  float* tokb  = smem + 9600;   // [16][17]
  float* tkmx  = smem + 9872;   // [64] (50 used)
  float* pp    = smem + 9936;   // [64]
  float* sctxv = smem + 10000;  // [300]
  int tid = threadIdx.x;
  for (int i = tid; i < NN * DDIM; i += 256)
    cand[i] = candg[(size_t)m * NN * DDIM + i];
  int nI = tid >> 4, tt = tid & 15;
  for (int tile = 0; tile < 4; tile++) {
    int cbase = tile * 16;
    __syncthreads();
    for (int i = tid; i < 16 * DDIM; i += 256) {
      int rr = i / DDIM, cc = i - rr * DDIM;
      int t = cbase + rr;
      ctx[rr * DDIM + cc] = (t < CTX_LL) ? ctx2g[(size_t)(m * CTX_LL + t) * DDIM + cc] : 0.f;
    }
    __syncthreads();
    const float4* ca = (const float4*)(cand + nI * DDIM);
    const float4* cb = (const float4*)(ctx + tt * DDIM);
    float dsum = 0.f;
#pragma unroll
    for (int c = 0; c < 75; c++) {
      float4 a = ca[c], b = cb[c];
      dsum += a.x * b.x + a.y * b.y + a.z * b.z + a.w * b.w;
    }
    tokb[nI * 17 + tt] = dsum;
    __syncthreads();
    if (tid < 16) {
      float mx = -1e30f;
      for (int nn = 0; nn < NN; nn++) mx = fmaxf(mx, tokb[nn * 17 + tid]);
      int t = cbase + tid;
      if (t < CTX_LL) tkmx[t] = mx;
    }
  }
  __syncthreads();
  if (tid < 64) {
    float v = (tid < CTX_LL) ? tkmx[tid] : -1e30f;
    float mx = v;
#pragma unroll
    for (int o = 32; o >= 1; o >>= 1) mx = fmaxf(mx, __shfl_xor(mx, o));
    float e = (tid < CTX_LL) ? expf(v - mx) : 0.f;
    float s = e;
#pragma unroll
    for (int o = 32; o >= 1; o >>= 1) s += __shfl_xor(s, o);
    pp[tid] = e / s;
  }
  __syncthreads();
  for (int d = tid; d < DDIM; d += 256) {
    float acc = 0.f;
    for (int t = 0; t < CTX_LL; t++)
      acc += pp[t] * ctx2g[(size_t)(m * CTX_LL + t) * DDIM + d];
    sctxv[d] = acc;
  }
  __syncthreads();
  int j = tid & 15;
  float dd = 0.f;
  for (int i = j; i < DDIM; i += 16) dd += cand[nI * DDIM + i] * sctxv[i];
#pragma unroll
  for (int o = 8; o >= 1; o >>= 1) dd += __shfl_xor(dd, o);
  if (j == 0) local_att[m * NN + nI] = dd;
}

// MEGA-MID: [0,192) conv_ms ; [192,512) scores dir0 ; [512,1072) scores dir1 ;
// [1072,1136) tok+ctxv.  Unified smem 14448 floats (57.8 KB, 2 blocks/CU).
__global__ __launch_bounds__(256) void mega_mid_kernel(
    const float* __restrict__ embed,
    const int* __restrict__ doc_vec,
    const int* __restrict__ body_vec,
    const float* __restrict__ msg,
    const float* __restrict__ WTms,
    const float* __restrict__ Bms,
    const float* __restrict__ candg,
    const float* __restrict__ ctx2g,
    float* __restrict__ ms,
    float* __restrict__ P,
    float* __restrict__ local_att) {
  __shared__ float smem[14448];
  int bid = blockIdx.x;
  if (bid < 192) {
    conv_ms_body(msg, WTms, Bms, ms, bid);
  } else if (bid < 512) {
    scores_body<0>(embed, doc_vec, body_vec, P, bid - 192, smem);
  } else if (bid < 1072) {
    scores_body<1>(embed, doc_vec, body_vec, P, bid - 512, smem);
  } else {
    tokctxv_body(candg, ctx2g, local_att, bid - 1072, smem);
  }
}

// ---------------------------------------------------------------------------
// PV + max-pool over q, both dirs merged (unchanged from R4).
__global__ __launch_bounds__(256) void attn_pv_kernel(
    const float* __restrict__ embed,
    const int* __restrict__ doc_vec,
    const int* __restrict__ body_vec,
    const float* __restrict__ P,
    float* __restrict__ pv0,   // [16][5][2][60]
    float* __restrict__ pv1) { // [16][5][4][60]
  int bid = blockIdx.x;
  int dir, pt, n, h;
  if (bid < 160) { dir = 0; h = bid % 5; n = (bid / 5) % 16; pt = bid / 80; }
  else { int b = bid - 160; dir = 1; h = b % 5; n = (b / 5) % 16; pt = b / 80; }
  int Lq = dir ? 200 : 100;
  int Lk = dir ? 100 : 200;
  int Lk4 = Lk >> 2;
  int K4STR = dir ? 27 : 51;
  const int* kids = dir ? doc_vec : body_vec + n * BODY_LL;
  __shared__ float4 Kt4[60 * 51];
  __shared__ float red[4][64];
  float* Ktf = (float*)Kt4;
  int RS = K4STR * 4;
  for (int idx = threadIdx.x; idx < Lk * 15; idx += 256) {
    int r = idx / 15, c = idx - r * 15;
    float4 v = *(const float4*)(embed + (size_t)kids[r] * DDIM + h * HDIM + c * 4);
    Ktf[(c * 4 + 0) * RS + r] = v.x;
    Ktf[(c * 4 + 1) * RS + r] = v.y;
    Ktf[(c * 4 + 2) * RS + r] = v.z;
    Ktf[(c * 4 + 3) * RS + r] = v.w;
  }
  __syncthreads();
  int lane = threadIdx.x & 63;
  int w = __builtin_amdgcn_readfirstlane(threadIdx.x >> 6);
  int dl = (lane < HDIM) ? lane : (HDIM - 1);
  const float4* Krow = Kt4 + dl * K4STR;
  const float* Pb = P + (size_t)((n * 2 + dir) * NHEADS + h) * 20000;
  float omax = -1e30f;
#pragma unroll
  for (int p = 0; p < 4; p++) {
    int q0 = pt * 64 + p * 16 + w * 4;
    int qa0 = min(q0, Lq - 1), qa1 = min(q0 + 1, Lq - 1);
    int qa2 = min(q0 + 2, Lq - 1), qa3 = min(q0 + 3, Lq - 1);
    const float4* P0 = (const float4*)(Pb + (size_t)qa0 * Lk);
    const float4* P1 = (const float4*)(Pb + (size_t)qa1 * Lk);
    const float4* P2 = (const float4*)(Pb + (size_t)qa2 * Lk);
    const float4* P3 = (const float4*)(Pb + (size_t)qa3 * Lk);
    float o0 = 0.f, o1 = 0.f, o2 = 0.f, o3 = 0.f;
    for (int k4 = 0; k4 < Lk4; k4++) {
      float4 pp0 = P0[k4], pp1 = P1[k4], pp2 = P2[k4], pp3 = P3[k4];
      float4 kk = Krow[k4];
      o0 += pp0.x * kk.x + pp0.y * kk.y + pp0.z * kk.z + pp0.w * kk.w;
      o1 += pp1.x * kk.x + pp1.y * kk.y + pp1.z * kk.z + pp1.w * kk.w;
      o2 += pp2.x * kk.x + pp2.y * kk.y + pp2.z * kk.z + pp2.w * kk.w;
      o3 += pp3.x * kk.x + pp3.y * kk.y + pp3.z * kk.z + pp3.w * kk.w;
    }
    if (q0 < Lq)     omax = fmaxf(omax, o0);
    if (q0 + 1 < Lq) omax = fmaxf(omax, o1);
    if (q0 + 2 < Lq) omax = fmaxf(omax, o2);
    if (q0 + 3 < Lq) omax = fmaxf(omax, o3);
  }
  red[threadIdx.x >> 6][lane] = omax;
  __syncthreads();
  if (threadIdx.x < 64 && lane < HDIM) {
    float m4 = fmaxf(fmaxf(red[0][lane], red[1][lane]),
                     fmaxf(red[2][lane], red[3][lane]));
    float* dst = dir ? pv1 + (size_t)((n * NHEADS + h) * 4 + pt) * HDIM
                     : pv0 + (size_t)((n * NHEADS + h) * 2 + pt) * HDIM;
    dst[lane] = m4;
  }
}

// ---------------------------------------------------------------------------
__global__ __launch_bounds__(256) void mlp_kernel(
    const float* __restrict__ pv0, const float* __restrict__ pv1,
    const float* __restrict__ w1, const float* __restrict__ b1,
    const float* __restrict__ w2, const float* __restrict__ b2,
    float* __restrict__ att_score) {
  int n = blockIdx.x, tid = threadIdx.x;
  __shared__ float comb[600];
  for (int idx = tid; idx < 300; idx += 256) {
    int h = idx / 60, d = idx - h * 60;
    float mx = -1e30f;
#pragma unroll
    for (int pt = 0; pt < 2; pt++)
      mx = fmaxf(mx, pv0[(size_t)((n * NHEADS + h) * 2 + pt) * HDIM + d]);
    comb[idx] = mx;
    mx = -1e30f;
#pragma unroll
    for (int pt = 0; pt < 4; pt++)
      mx = fmaxf(mx, pv1[(size_t)((n * NHEADS + h) * 4 + pt) * HDIM + d]);
    comb[300 + idx] = mx;
  }
  __syncthreads();
  float partial = 0.f;
  for (int j = tid; j < 300; j += 256) {
    float hh = b1[j];
    for (int k = 0; k < 600; k++) hh += comb[k] * w1[k * 300 + j];
    partial += fmaxf(hh, 0.f) * w2[j];
  }
  __shared__ float redd[256];
  redd[tid] = partial;
  __syncthreads();
  for (int s = 128; s > 0; s >>= 1) {
    if (tid < s) redd[tid] += redd[tid + s];
    __syncthreads();
  }
  if (tid == 0) att_score[n] = 1.0f / (1.0f + expf(-(redd[0] + b2[0])));
}

// ---------------------------------------------------------------------------
__global__ __launch_bounds__(256) void final_kernel(
    const float* __restrict__ ms,
    const float* __restrict__ mc,
    const float* __restrict__ title,
    const float* __restrict__ bert,
    const float* __restrict__ att_score,
    const float* __restrict__ m2c_prior,
    const float* __restrict__ hand,
    const float* __restrict__ local_att,
    const float* __restrict__ w7,
    const float* __restrict__ b7,
    float* __restrict__ out) {
  int m = blockIdx.x, tid = threadIdx.x;
  __shared__ float sms[FNUM], smc[FNUM], smd[FNUM];
  __shared__ float snorm[3], sscore[16], wred[3][4];
  for (int i = tid; i < FNUM; i += 256) {
    sms[i] = ms[m * FNUM + i];
    smc[i] = mc[m * FNUM + i];
    smd[i] = bert[i];
  }
  __syncthreads();
  float p1 = 0.f, p2 = 0.f, p3 = 0.f;
  for (int i = tid; i < FNUM; i += 256) {
    float a = sms[i], b = smc[i], c = smd[i];
    p1 += a * a; p2 += b * b; p3 += c * c;
  }
#pragma unroll
  for (int o = 32; o >= 1; o >>= 1) {
    p1 += __shfl_xor(p1, o); p2 += __shfl_xor(p2, o); p3 += __shfl_xor(p3, o);
  }
  int wid = tid >> 6, lane = tid & 63;
  if (lane == 0) { wred[0][wid] = p1; wred[1][wid] = p2; wred[2][wid] = p3; }
  __syncthreads();
  if (tid == 0) {
    snorm[0] = fmaxf(sqrtf(wred[0][0] + wred[0][1] + wred[0][2] + wred[0][3]), 1e-6f);
    snorm[1] = fmaxf(sqrtf(wred[1][0] + wred[1][1] + wred[1][2] + wred[1][3]), 1e-6f);
    snorm[2] = fmaxf(sqrtf(wred[2][0] + wred[2][1] + wred[2][2] + wred[2][3]), 1e-6f);
  }
  __syncthreads();
  int nI = tid >> 4, j = tid & 15;
  float d1 = 0.f, d2 = 0.f, d3 = 0.f, d4 = 0.f;
  for (int i = j; i < FNUM; i += 16) {
    float t = title[nI * FNUM + i];
    d1 += sms[i] * t; d2 += smc[i] * t; d3 += smd[i] * t; d4 += t * t;
  }
#pragma unroll
  for (int o = 8; o >= 1; o >>= 1) {
    d1 += __shfl_xor(d1, o); d2 += __shfl_xor(d2, o);
    d3 += __shfl_xor(d3, o); d4 += __shfl_xor(d4, o);
  }
  if (j == 0) {
    float nt = fmaxf(sqrtf(d4), 1e-6f);
    float cos_st = d1 / (snorm[0] * nt);
    float cos_ct = d2 / (snorm[1] * nt);
    float cos_dt = d3 / (snorm[2] * nt);
    float score = hand[nI] * w7[0] + m2c_prior[nI] * w7[1] +
                  local_att[m * NN + nI] * w7[2] + att_score[nI] * w7[3] +
                  cos_st * w7[4] + cos_dt * w7[5] + cos_ct * w7[6] + b7[0];
    sscore[nI] = score;
  }
  __syncthreads();
  if (tid < 16) {
    float x = sscore[tid];
    float s = x;
#pragma unroll
    for (int o = 8; o >= 1; o >>= 1) s += __shfl_xor(s, o);
    float mu = s * (1.0f / 16.0f);
    float dv = (x - mu) * (x - mu);
    float vs = dv;
#pragma unroll
    for (int o = 8; o >= 1; o >>= 1) vs += __shfl_xor(vs, o);
    float sd = sqrtf(vs * (1.0f / 15.0f));
    float z = (x - mu) / sd;
    float zm = z;
#pragma unroll
    for (int o = 8; o >= 1; o >>= 1) zm = fmaxf(zm, __shfl_xor(zm, o));
    float e = expf(z - zm);
    float es = e;
#pragma unroll
    for (int o = 8; o >= 1; o >>= 1) es += __shfl_xor(es, o);
    float sm = e / es;
    float zmin = z;
#pragma unroll
    for (int o = 8; o >= 1; o >>= 1) zmin = fminf(zmin, __shfl_xor(zmin, o));
    float u0 = (z + 1.0f - zmin) / (zm - zmin);
    float us = u0;
#pragma unroll
    for (int o = 8; o >= 1; o >>= 1) us += __shfl_xor(us, o);
    float u = u0 / us;
    out[m * NN + tid] = z;
    out[MM * NN + m * NN + tid] = sm;
    out[2 * MM * NN + m * NN + tid] = u;
  }
}

// ---------------------------------------------------------------------------
extern "C" void kernel_launch(void* const* d_in, const int* in_sizes, int n_in,
                              void* d_out, int out_size, void* d_ws, size_t ws_size,
                              hipStream_t stream) {
  const int*   mention_vec   = (const int*)d_in[3];
  const int*   context_vec   = (const int*)d_in[4];
  const int*   doc_vec       = (const int*)d_in[5];
  const float* title_vec     = (const float*)d_in[6];
  const int*   body_vec      = (const int*)d_in[7];
  const float* m2c_prior     = (const float*)d_in[9];
  const int*   men2cands     = (const int*)d_in[10];
  const int*   contexts_ids  = (const int*)d_in[11];
  const float* hand_features = (const float*)d_in[12];
  const float* bert_doc_vec  = (const float*)d_in[13];
  const float* embed_table   = (const float*)d_in[14];
  const float* conv_ms_w     = (const float*)d_in[15];
  const float* conv_ms_b     = (const float*)d_in[16];
  const float* conv_mc_w     = (const float*)d_in[17];
  const float* conv_mc_b     = (const float*)d_in[18];
  const float* layer_local_w = (const float*)d_in[19];
  const float* layer_local_b = (const float*)d_in[20];
  const float* att_w1        = (const float*)d_in[21];
  const float* att_b1        = (const float*)d_in[22];
  const float* att_w2        = (const float*)d_in[23];
  const float* att_b2        = (const float*)d_in[24];

  float* ws     = (float*)d_ws;
  float* msg    = ws + OFF_MSG;
  float* ctx2g  = ws + OFF_CTX2G;
  float* candg  = ws + OFF_CANDG;
  float* ms     = ws + OFF_MS;
  float* mc     = ws + OFF_MC;
  float* pv0    = ws + OFF_PV0;
  float* pv1    = ws + OFF_PV1;
  float* att_sc = ws + OFF_ASC;
  float* latt   = ws + OFF_LATT;
  u16*   Abf    = (u16*)(ws + OFF_ABF);
  u16*   WTmc   = (u16*)(ws + OFF_WTMC);
  float* WTms   = ws + OFF_WTMS;
  float* P      = ws + OFF_P;
  float* out    = (float*)d_out;

  mega_prep_kernel<<<dim3(18378), dim3(256), 0, stream>>>(
      embed_table, mention_vec, context_vec, contexts_ids, men2cands,
      conv_mc_w, conv_ms_w, ws, mc, (u32*)Abf, (u32*)WTmc, WTms);
  conv_gemm_kernel<<<dim3(GN / 64, GM / 64), dim3(256), 0, stream>>>(
      Abf, WTmc, conv_mc_b, mc);
  mega_mid_kernel<<<dim3(1136), dim3(256), 0, stream>>>(
      embed_table, doc_vec, body_vec, msg, WTms, conv_ms_b, candg, ctx2g,
      ms, P, latt);
  attn_pv_kernel<<<dim3(480), dim3(256), 0, stream>>>(
      embed_table, doc_vec, body_vec, P, pv0, pv1);
  mlp_kernel<<<dim3(NN), dim3(256), 0, stream>>>(pv0, pv1, att_w1, att_b1, att_w2, att_b2, att_sc);
  final_kernel<<<dim3(MM), dim3(256), 0, stream>>>(
      ms, mc, title_vec, bert_doc_vec, att_sc, m2c_prior, hand_features,
      latt, layer_local_w, layer_local_b, out);
}